// Round 6
// baseline (322.086 us; speedup 1.0000x reference)
//
#include <hip/hip_runtime.h>
#include <hip/hip_bf16.h>
#include <stdint.h>

typedef unsigned short u16;
typedef unsigned int u32;
typedef __attribute__((ext_vector_type(8))) short bf16x8;
typedef __attribute__((ext_vector_type(4))) float f32x4;

typedef __attribute__((address_space(3))) void lds_void;
typedef const __attribute__((address_space(1))) void gbl_void;

#define SIDE 4194304u   // 4M elems = one side's [B,H,2048,64] / [4096,1024]
#define BHSTR 131072u   // 2048*64 per (b,h)

static __device__ __forceinline__ u16 f2bf(float f) {
  union { __hip_bfloat16 b; u16 u; } cv;
  cv.b = __float2bfloat16(f);
  return cv.u;
}
static __device__ __forceinline__ float bf2f(u16 u) {
  union { __hip_bfloat16 b; u16 u; } cv;
  cv.u = u;
  return __bfloat162float(cv.b);
}

// v_permlane16_swap_b32: row1(a)<->row0(b), row3(a)<->row2(b) (16-lane rows)
static __device__ __forceinline__ void pl16swap(u32& a, u32& b) {
#if __has_builtin(__builtin_amdgcn_permlane16_swap)
  typedef __attribute__((ext_vector_type(2))) unsigned int u32x2;
  u32x2 r = __builtin_amdgcn_permlane16_swap(a, b, 0, 0);
  a = r[0];
  b = r[1];
#else
  asm volatile("v_permlane16_swap_b32 %0, %1" : "+v"(a), "+v"(b));
#endif
}

// ---------------- input convert: a,b fp32 -> bf16 row-major ----------------
__global__ __launch_bounds__(256) void k_cvt_in(const float* __restrict__ a,
                                                const float* __restrict__ b,
                                                u16* __restrict__ dst) {
  int z = blockIdx.y;
  const float* src = z ? b : a;
  size_t i = ((size_t)blockIdx.x * 256 + threadIdx.x) * 8;
  float4 x0 = *(const float4*)(src + i);
  float4 x1 = *(const float4*)(src + i + 4);
  u16 t[8] = {f2bf(x0.x), f2bf(x0.y), f2bf(x0.z), f2bf(x0.w),
              f2bf(x1.x), f2bf(x1.y), f2bf(x1.z), f2bf(x1.w)};
  *(uint4*)(dst + (size_t)z * SIDE + i) = *(uint4*)t;
}

// ---------------- bias convert (fp32 -> bf16, concat, scale z0) -----------
// scale = 1/sqrt(D) * log2(e) so scores feed exp2 directly
__global__ __launch_bounds__(256) void k_cvt_bias(
    const float* s0, const float* s1, const float* s2, const float* s3,
    const float* s4, const float* s5, u16* __restrict__ dst) {
  const float* srcs[6] = {s0, s1, s2, s3, s4, s5};
  int z = blockIdx.y;
  int i = blockIdx.x * 256 + threadIdx.x;
  float sc = (z == 0) ? 0.18033688011112042f : 1.0f;  // 0.125 * log2(e)
  dst[z * 1024 + i] = f2bf(srcs[z][i] * sc);
}

// ---------------- weight transpose fp32 -> bf16, concat, scale z0 ---------
__global__ __launch_bounds__(256) void k_transpose_w(
    const float* a0, const float* a1, const float* a2, const float* a3,
    const float* a4, const float* a5,
    u16* d0, u16* d1, u16* d2, u16* d3, u16* d4, u16* d5) {
  __shared__ u16 tile[64][72];
  const float* srcs[6] = {a0, a1, a2, a3, a4, a5};
  u16* dsts[6] = {d0, d1, d2, d3, d4, d5};
  int z = blockIdx.z;
  float sc = (z == 0) ? 0.18033688011112042f : 1.0f;  // 0.125 * log2(e)
  const float* src = srcs[z] + (size_t)(blockIdx.y * 64) * 1024 + blockIdx.x * 64;
  int t = threadIdx.x;
  int row = t >> 2, c4 = t & 3;
#pragma unroll
  for (int p = 0; p < 2; ++p) {
    int col = c4 * 8 + p * 32;
    const float* sf = src + (size_t)row * 1024 + col;
    float4 x0 = *(const float4*)sf;
    float4 x1 = *(const float4*)(sf + 4);
    u16 tmp[8] = {f2bf(x0.x * sc), f2bf(x0.y * sc), f2bf(x0.z * sc), f2bf(x0.w * sc),
                  f2bf(x1.x * sc), f2bf(x1.y * sc), f2bf(x1.z * sc), f2bf(x1.w * sc)};
    *(uint4*)(&tile[row][col]) = *(uint4*)tmp;
  }
  __syncthreads();
  u16* dst = dsts[z] + (size_t)(blockIdx.x * 64) * 1024 + blockIdx.y * 64;
#pragma unroll
  for (int p = 0; p < 2; ++p) {
    int col = c4 * 8 + p * 32;
    u16 tmp[8];
#pragma unroll
    for (int i = 0; i < 8; ++i) tmp[i] = tile[col + i][row];
    *(uint4*)(dst + (size_t)row * 1024 + col) = *(uint4*)tmp;
  }
}

// ---------------- QKV projection: [4096,1024]bf16 @ WtAB[2048,1024]^T -----
__global__ __launch_bounds__(256) void k_gemm_qkv(
    const u16* __restrict__ Aall, const u16* __restrict__ WtA,
    const u16* __restrict__ WtB, const u16* __restrict__ bias,
    u16* __restrict__ qkbuf, u16* __restrict__ vbuf) {
  __shared__ u16 Sh[8192];
  u16* As = Sh;
  u16* Bs = Sh + 4096;
  int tid = threadIdx.x;
  int wave = tid >> 6, lane = tid & 63;
  int quad = lane >> 4, lrow = lane & 15;
  int wr = wave >> 1, wc = wave & 1;
  int z = blockIdx.z;
  int m0 = blockIdx.y * 128, n0 = blockIdx.x * 128;
  const u16* A = Aall + (size_t)z * SIDE;
  const u16* Wt = z ? WtB : WtA;
  const u16* bi = bias + (size_t)z * 2048;

  f32x4 acc[4][4] = {};
  int srow = 32 * wave + (lane >> 2);
  int scol = (lane & 3) * 8;
  const u16* gA = A + (size_t)(m0 + srow) * 1024 + scol;
  const u16* gB = Wt + (size_t)(n0 + srow) * 1024 + scol;
  u16* lA = &As[(32 * wave) * 32];
  u16* lB = &Bs[(32 * wave) * 32];

  for (int k0 = 0; k0 < 1024; k0 += 32) {
    __syncthreads();
#pragma unroll
    for (int j = 0; j < 2; ++j) {
      __builtin_amdgcn_global_load_lds((gbl_void*)(gA + (size_t)(16 * j) * 1024 + k0),
                                       (lds_void*)(lA + 16 * j * 32), 16, 0, 0);
      __builtin_amdgcn_global_load_lds((gbl_void*)(gB + (size_t)(16 * j) * 1024 + k0),
                                       (lds_void*)(lB + 16 * j * 32), 16, 0, 0);
    }
    __syncthreads();
    bf16x8 af[4], bfr[4];
#pragma unroll
    for (int i = 0; i < 4; ++i)
      af[i] = *(const bf16x8*)&As[(64 * wr + 16 * i + lrow) * 32 + 8 * quad];
#pragma unroll
    for (int j = 0; j < 4; ++j)
      bfr[j] = *(const bf16x8*)&Bs[(64 * wc + 16 * j + lrow) * 32 + 8 * quad];
#pragma unroll
    for (int i = 0; i < 4; ++i)
#pragma unroll
      for (int j = 0; j < 4; ++j)
        acc[i][j] = __builtin_amdgcn_mfma_f32_16x16x32_bf16(af[i], bfr[j], acc[i][j], 0, 0, 0);
  }

  float bv[4];
#pragma unroll
  for (int j = 0; j < 4; ++j) bv[j] = bf2f(bi[n0 + 64 * wc + 16 * j + lrow]);

  int x = blockIdx.x;
  bool isv = (x >= 8);
  int h = (isv ? 2 * (x - 8) : 2 * x) + wc;
  u16* dst = (isv ? vbuf : qkbuf) + (size_t)z * SIDE;
  u16* lw = Sh + wave * 1216;  // 16 rows * stride 76 per wave

  __syncthreads();  // all waves done reading As/Bs
#pragma unroll
  for (int i = 0; i < 4; ++i) {
#pragma unroll
    for (int j = 0; j < 4; ++j)
#pragma unroll
      for (int r = 0; r < 4; ++r)
        lw[(4 * quad + r) * 76 + 16 * j + lrow] = f2bf(acc[i][j][r] + bv[j]);
    asm volatile("s_waitcnt lgkmcnt(0)" ::: "memory");
    int row = lane >> 2, cg = (lane & 3) * 16;
    int rg = m0 + 64 * wr + 16 * i + row;
    int bb = rg >> 11, rl = rg & 2047;
    u16* dr = dst + (size_t)(bb * 16 + h) * BHSTR + (size_t)rl * 64 + cg;
    uint2 w0 = *(const uint2*)&lw[row * 76 + cg];
    uint2 w1 = *(const uint2*)&lw[row * 76 + cg + 4];
    uint2 w2 = *(const uint2*)&lw[row * 76 + cg + 8];
    uint2 w3 = *(const uint2*)&lw[row * 76 + cg + 12];
    uint4 o0 = {w0.x, w0.y, w1.x, w1.y};
    uint4 o1 = {w2.x, w2.y, w3.x, w3.y};
    *(uint4*)dr = o0;
    *(uint4*)(dr + 8) = o1;
    asm volatile("s_waitcnt lgkmcnt(0)" ::: "memory");  // WAR fence before next pass
  }
}

// ---------------- V transpose per head: [sbh][2048][64] -> [sbh][64][2048] --
__global__ __launch_bounds__(256) void k_transpose_v(const u16* __restrict__ v,
                                                     u16* __restrict__ vt) {
  __shared__ u16 tile[64][72];
  int sbh = blockIdx.y;
  int n0 = blockIdx.x * 64;
  const u16* src = v + (size_t)sbh * BHSTR + (size_t)n0 * 64;
  u16* dst = vt + (size_t)sbh * BHSTR + n0;
  int t = threadIdx.x;
  int row = t >> 2, c4 = t & 3;
#pragma unroll
  for (int p = 0; p < 2; ++p) {
    int col = c4 * 8 + p * 32;
    uint4 q = *(const uint4*)(src + (size_t)row * 64 + col);
    *(uint4*)(&tile[row][col]) = q;
  }
  __syncthreads();
#pragma unroll
  for (int p = 0; p < 2; ++p) {
    int col = c4 * 8 + p * 32;
    u16 tmp[8];
#pragma unroll
    for (int i = 0; i < 8; ++i) tmp[i] = tile[col + i][row];
    *(uint4*)(dst + (size_t)row * 2048 + col) = *(uint4*)tmp;
  }
}

// ---------------- fused dual-softmax attention, both sides ----------------
// z=0: Q=aq,K=bq,V=bv -> a_ctx ; z=1: Q=bq,K=aq,V=av -> b_ctx
// KVBLK=64 rounds, conflict-free 128B-stride XOR layout, Q in regs,
// P in registers via v_permlane16_swap (ATT_BODY byte-identical to the
// hardware-verified r3 version).  T4: raw s_barrier + counted
// s_waitcnt vmcnt(4) with THREE LDS buffers / depth-2 prefetch —
// loads stay in flight across barriers (~2 rounds to land, covers HBM
// miss latency) instead of the compiler's vmcnt(0) drain at __syncthreads.
__global__ __launch_bounds__(256, 4) void k_attn(
    const u16* __restrict__ qk, const u16* __restrict__ vt,
    u16* __restrict__ ctx) {
  __shared__ u16 Ks[3 * 4096];   // [3][64 s][64 d], granule-swizzled
  __shared__ u16 Vs[3 * 4096];   // [3][64 d][64 s], granule-swizzled
  int tid = threadIdx.x;
  int wave = tid >> 6, lane = tid & 63;
  int quad = lane >> 4, lrow = lane & 15;
  int z = blockIdx.z, bh = blockIdx.x;   // x=bh: l-tiles of one (z,bh) share an XCD
  int l0 = blockIdx.y * 128;
  const u16* Qb = qk + (size_t)z * SIDE + (size_t)bh * BHSTR + (size_t)l0 * 64;
  const u16* Kb = qk + (size_t)(1 - z) * SIDE + (size_t)bh * BHSTR;
  const u16* Vtb = vt + (size_t)(1 - z) * SIDE + (size_t)bh * BHSTR;

  // Q -> registers: wave owns rows 32*wave .. 32*wave+31
  bf16x8 qf[2][2];
#pragma unroll
  for (int rt = 0; rt < 2; ++rt) {
    int lq = 32 * wave + 16 * rt + lrow;
    qf[rt][0] = *(const bf16x8*)&Qb[(size_t)lq * 64 + 8 * quad];
    qf[rt][1] = *(const bf16x8*)&Qb[(size_t)lq * 64 + 32 + 8 * quad];
  }

  // staging lane constants: 512 granules per tile, 2 per thread (p=0,1)
  int r0 = tid >> 3, c0 = tid & 7;
  int r1 = (256 + tid) >> 3;             // c1 == c0
  const u16* kS0 = Kb + (size_t)r0 * 64 + ((c0 ^ (r0 & 7)) * 8);
  const u16* kS1 = Kb + (size_t)r1 * 64 + ((c0 ^ (r1 & 7)) * 8);
  const u16* vS0 = Vtb + (size_t)r0 * 2048 + ((c0 ^ (r0 & 7)) * 8);
  const u16* vS1 = Vtb + (size_t)r1 * 2048 + ((c0 ^ (r1 & 7)) * 8);
  u16* kD0 = Ks + (wave * 64) * 8;       // uniform base; HW adds lane*16B
  u16* kD1 = Ks + (256 + wave * 64) * 8;
  u16* vD0 = Vs + (wave * 64) * 8;
  u16* vD1 = Vs + (256 + wave * 64) * 8;

  bf16x8 ones;
  {
    short o = 0x3F80;  // bf16 1.0
#pragma unroll
    for (int i = 0; i < 8; ++i) ones[i] = o;
  }

  f32x4 cacc[2][4] = {};
  f32x4 asum[2] = {};
  int gsq = 2 * (quad & 1) + (quad >> 1);  // V granule permutation [0,2,1,3]

#define STAGE(BUFOFF, IT)                                                        \
  __builtin_amdgcn_global_load_lds((gbl_void*)(kS0 + (size_t)(IT)*4096),         \
                                   (lds_void*)(kD0 + (BUFOFF)), 16, 0, 0);       \
  __builtin_amdgcn_global_load_lds((gbl_void*)(kS1 + (size_t)(IT)*4096),         \
                                   (lds_void*)(kD1 + (BUFOFF)), 16, 0, 0);       \
  __builtin_amdgcn_global_load_lds((gbl_void*)(vS0 + (size_t)(IT)*64),           \
                                   (lds_void*)(vD0 + (BUFOFF)), 16, 0, 0);       \
  __builtin_amdgcn_global_load_lds((gbl_void*)(vS1 + (size_t)(IT)*64),           \
                                   (lds_void*)(vD1 + (BUFOFF)), 16, 0, 0);

// counted wait: own STAGE(t) loads retired (<=4 newest outstanding), then
// barrier => ALL waves' STAGE(t) writes visible.  "memory" clobber +
// sched_barrier(0) stop ds_read hoisting above the wait (rule #18).
#define WAITN(N)                                                                 \
  asm volatile("s_waitcnt vmcnt(" #N ")" ::: "memory");                          \
  __builtin_amdgcn_s_barrier();                                                  \
  __builtin_amdgcn_sched_barrier(0);

#define ATT_BODY(BUFOFF)                                                         \
  {                                                                              \
    const u16* KsC = Ks + (BUFOFF);                                              \
    const u16* VsC = Vs + (BUFOFF);                                              \
    u32 X[2][4], Y[2][4];                                                        \
    _Pragma("unroll") for (int j = 0; j < 4; ++j) {                              \
      int kr = 16 * j + lrow;                                                    \
      bf16x8 kf0 = *(const bf16x8*)&KsC[(kr * 8 + (quad ^ (kr & 7))) * 8];       \
      bf16x8 kf1 = *(const bf16x8*)&KsC[(kr * 8 + ((quad + 4) ^ (kr & 7))) * 8]; \
      _Pragma("unroll") for (int rt = 0; rt < 2; ++rt) {                         \
        f32x4 s = {};                                                            \
        s = __builtin_amdgcn_mfma_f32_16x16x32_bf16(kf0, qf[rt][0], s, 0, 0, 0); \
        s = __builtin_amdgcn_mfma_f32_16x16x32_bf16(kf1, qf[rt][1], s, 0, 0, 0); \
        float e0 = exp2f(s[0]), e1 = exp2f(s[1]);                                \
        float e2 = exp2f(s[2]), e3 = exp2f(s[3]);                                \
        X[rt][j] = ((u32)f2bf(e1) << 16) | (u32)f2bf(e0);                        \
        Y[rt][j] = ((u32)f2bf(e3) << 16) | (u32)f2bf(e2);                        \
      }                                                                          \
    }                                                                            \
    bf16x8 pf[2][2];                                                             \
    _Pragma("unroll") for (int rt = 0; rt < 2; ++rt) {                           \
      pl16swap(X[rt][0], X[rt][1]);                                              \
      pl16swap(Y[rt][0], Y[rt][1]);                                              \
      pl16swap(X[rt][2], X[rt][3]);                                              \
      pl16swap(Y[rt][2], Y[rt][3]);                                              \
      union { u32 d[4]; bf16x8 v; } u0, u1;                                      \
      u0.d[0] = X[rt][0]; u0.d[1] = Y[rt][0];                                    \
      u0.d[2] = X[rt][1]; u0.d[3] = Y[rt][1];                                    \
      u1.d[0] = X[rt][2]; u1.d[1] = Y[rt][2];                                    \
      u1.d[2] = X[rt][3]; u1.d[3] = Y[rt][3];                                    \
      pf[rt][0] = u0.v;                                                          \
      pf[rt][1] = u1.v;                                                          \
    }                                                                            \
    _Pragma("unroll") for (int jd = 0; jd < 4; ++jd) {                           \
      int vr = 16 * jd + lrow;                                                   \
      bf16x8 vf0 = *(const bf16x8*)&VsC[(vr * 8 + (gsq ^ (vr & 7))) * 8];        \
      bf16x8 vf1 = *(const bf16x8*)&VsC[(vr * 8 + ((gsq | 4) ^ (vr & 7))) * 8];  \
      _Pragma("unroll") for (int rt = 0; rt < 2; ++rt) {                         \
        cacc[rt][jd] = __builtin_amdgcn_mfma_f32_16x16x32_bf16(pf[rt][0], vf0, cacc[rt][jd], 0, 0, 0); \
        cacc[rt][jd] = __builtin_amdgcn_mfma_f32_16x16x32_bf16(pf[rt][1], vf1, cacc[rt][jd], 0, 0, 0); \
      }                                                                          \
    }                                                                            \
    _Pragma("unroll") for (int rt = 0; rt < 2; ++rt) {                           \
      asum[rt] = __builtin_amdgcn_mfma_f32_16x16x32_bf16(pf[rt][0], ones, asum[rt], 0, 0, 0); \
      asum[rt] = __builtin_amdgcn_mfma_f32_16x16x32_bf16(pf[rt][1], ones, asum[rt], 0, 0, 0); \
    }                                                                            \
  }

  // prologue: depth-2 prefetch (rounds 0,1 into buffers 0,1)
  STAGE(0, 0)
  STAGE(4096, 1)

#pragma unroll 1
  for (int t2 = 0; t2 < 10; ++t2) {
    int t = 3 * t2;
    WAITN(4) STAGE(8192, t + 2) ATT_BODY(0)
    WAITN(4) STAGE(0, t + 3)    ATT_BODY(4096)
    WAITN(4) STAGE(4096, t + 4) ATT_BODY(8192)
  }
  // epilogue rounds 30 (buf0, nothing left to stage) and 31 (buf1)
  WAITN(4) ATT_BODY(0)
  WAITN(0) ATT_BODY(4096)
#undef ATT_BODY
#undef WAITN
#undef STAGE

  int bb = bh >> 4, h = bh & 15;
  u16* Ob = ctx + (size_t)z * SIDE + (size_t)(bb * 2048 + l0) * 1024 + h * 64;
#pragma unroll
  for (int rt = 0; rt < 2; ++rt) {
#pragma unroll
    for (int r = 0; r < 4; ++r) {
      float rinv = 1.0f / asum[rt][r];
      int l = 32 * wave + 16 * rt + 4 * quad + r;
#pragma unroll
      for (int j = 0; j < 4; ++j)
        Ob[(size_t)l * 1024 + 16 * j + lrow] = f2bf(cacc[rt][j][r] * rinv);
    }
  }
}

// ---------------- O projection: ctx[4096,1024]bf16 @ WtO^T + bias -> fp32 --
__global__ __launch_bounds__(256) void k_gemm_o(
    const u16* __restrict__ ctx, const u16* __restrict__ WtO,
    const u16* __restrict__ bias, float* __restrict__ out) {
  __shared__ u16 As[128 * 32];
  __shared__ u16 Bs[128 * 32];
  int tid = threadIdx.x;
  int wave = tid >> 6, lane = tid & 63;
  int quad = lane >> 4, lrow = lane & 15;
  int wr = wave >> 1, wc = wave & 1;
  int z = blockIdx.z;
  int m0 = blockIdx.y * 128, n0 = blockIdx.x * 128;
  const u16* A = ctx + (size_t)z * SIDE;
  const u16* Wt = WtO + (size_t)z * 1048576;
  const u16* bi = bias + (size_t)z * 1024;
  float* C = out + (size_t)z * SIDE;

  f32x4 acc[4][4] = {};
  int srow = 32 * wave + (lane >> 2);
  int scol = (lane & 3) * 8;
  const u16* gA = A + (size_t)(m0 + srow) * 1024 + scol;
  const u16* gB = Wt + (size_t)(n0 + srow) * 1024 + scol;
  u16* lA = &As[(32 * wave) * 32];
  u16* lB = &Bs[(32 * wave) * 32];

  for (int k0 = 0; k0 < 1024; k0 += 32) {
    __syncthreads();
#pragma unroll
    for (int j = 0; j < 2; ++j) {
      __builtin_amdgcn_global_load_lds((gbl_void*)(gA + (size_t)(16 * j) * 1024 + k0),
                                       (lds_void*)(lA + 16 * j * 32), 16, 0, 0);
      __builtin_amdgcn_global_load_lds((gbl_void*)(gB + (size_t)(16 * j) * 1024 + k0),
                                       (lds_void*)(lB + 16 * j * 32), 16, 0, 0);
    }
    __syncthreads();
    bf16x8 af[4], bfr[4];
#pragma unroll
    for (int i = 0; i < 4; ++i)
      af[i] = *(const bf16x8*)&As[(64 * wr + 16 * i + lrow) * 32 + 8 * quad];
#pragma unroll
    for (int j = 0; j < 4; ++j)
      bfr[j] = *(const bf16x8*)&Bs[(64 * wc + 16 * j + lrow) * 32 + 8 * quad];
#pragma unroll
    for (int i = 0; i < 4; ++i)
#pragma unroll
      for (int j = 0; j < 4; ++j)
        acc[i][j] = __builtin_amdgcn_mfma_f32_16x16x32_bf16(af[i], bfr[j], acc[i][j], 0, 0, 0);
  }

  float bv[4];
#pragma unroll
  for (int j = 0; j < 4; ++j) bv[j] = bf2f(bi[n0 + 64 * wc + 16 * j + lrow]);
#pragma unroll
  for (int i = 0; i < 4; ++i) {
    int row = m0 + 64 * wr + 16 * i + 4 * quad;
#pragma unroll
    for (int j = 0; j < 4; ++j) {
      int col = n0 + 64 * wc + 16 * j + lrow;
#pragma unroll
      for (int r = 0; r < 4; ++r)
        C[(size_t)(row + r) * 1024 + col] = acc[i][j][r] + bv[j];
    }
  }
}

extern "C" void kernel_launch(void* const* d_in, const int* in_sizes, int n_in,
                              void* d_out, int out_size, void* d_ws, size_t ws_size,
                              hipStream_t stream) {
  (void)in_sizes; (void)n_in; (void)out_size; (void)ws_size;
  const size_t M1 = 1048576u;
  u16* ws = (u16*)d_ws;
  u16* wtA   = ws;             // [2048,1024] concat(Wa_qk^T*0.125*log2e, Wa_v^T)
  u16* wtB   = ws + 2 * M1;    // [2048,1024] concat(Wb_qk^T, Wb_v^T)
  u16* wtO   = ws + 4 * M1;    // [2048,1024] concat(Wa_o^T, Wb_o^T)
  u16* biasQ = ws + 6 * M1;    // [2,2048]
  u16* biasO = ws + 6 * M1 + 4096;  // [2,1024]
  u16* ab    = ws + 7 * M1;    // [2][4096,1024] bf16 inputs (dead after QKV)
  u16* vt    = ab;             // alias: [2][bh][64][2048]
  u16* qkbuf = ws + 15 * M1;   // [2][bh][2048][64]
  u16* vbuf  = ws + 23 * M1;   // [2][bh][2048][64] (dead after transpose_v)
  u16* ctx   = vbuf;           // alias: [2][4096,1024]

  dim3 blk(256);
  k_cvt_in<<<dim3(2048, 2), blk, 0, stream>>>((const float*)d_in[0],
                                              (const float*)d_in[1], ab);
  k_cvt_bias<<<dim3(4, 6), blk, 0, stream>>>(
      (const float*)d_in[3], (const float*)d_in[5], (const float*)d_in[7],
      (const float*)d_in[9], (const float*)d_in[11], (const float*)d_in[13], biasQ);
  k_transpose_w<<<dim3(16, 16, 6), blk, 0, stream>>>(
      (const float*)d_in[2], (const float*)d_in[4], (const float*)d_in[6],
      (const float*)d_in[8], (const float*)d_in[10], (const float*)d_in[12],
      wtA, wtA + M1, wtB, wtB + M1, wtO, wtO + M1);
  k_gemm_qkv<<<dim3(16, 32, 2), blk, 0, stream>>>(ab, wtA, wtB, biasQ, qkbuf, vbuf);
  k_transpose_v<<<dim3(32, 64), blk, 0, stream>>>(vbuf, vt);
  k_attn<<<dim3(32, 16, 2), blk, 0, stream>>>(qkbuf, vt, ctx);
  k_gemm_o<<<dim3(8, 32, 2), blk, 0, stream>>>(ctx, wtO, biasO, (float*)d_out);
}

// Round 7
// 320.991 us; speedup vs baseline: 1.0034x; 1.0034x over previous
//
#include <hip/hip_runtime.h>
#include <hip/hip_bf16.h>
#include <stdint.h>

typedef unsigned short u16;
typedef unsigned int u32;
typedef __attribute__((ext_vector_type(8))) short bf16x8;
typedef __attribute__((ext_vector_type(4))) float f32x4;

typedef __attribute__((address_space(3))) void lds_void;
typedef const __attribute__((address_space(1))) void gbl_void;

#define SIDE 4194304u   // 4M elems = one side's [B,H,2048,64] / [4096,1024]
#define BHSTR 131072u   // 2048*64 per (b,h)

static __device__ __forceinline__ u16 f2bf(float f) {
  union { __hip_bfloat16 b; u16 u; } cv;
  cv.b = __float2bfloat16(f);
  return cv.u;
}
static __device__ __forceinline__ float bf2f(u16 u) {
  union { __hip_bfloat16 b; u16 u; } cv;
  cv.u = u;
  return __bfloat162float(cv.b);
}

// ---------------- input convert: a,b fp32 -> bf16 row-major ----------------
__global__ __launch_bounds__(256) void k_cvt_in(const float* __restrict__ a,
                                                const float* __restrict__ b,
                                                u16* __restrict__ dst) {
  int z = blockIdx.y;
  const float* src = z ? b : a;
  size_t i = ((size_t)blockIdx.x * 256 + threadIdx.x) * 8;
  float4 x0 = *(const float4*)(src + i);
  float4 x1 = *(const float4*)(src + i + 4);
  u16 t[8] = {f2bf(x0.x), f2bf(x0.y), f2bf(x0.z), f2bf(x0.w),
              f2bf(x1.x), f2bf(x1.y), f2bf(x1.z), f2bf(x1.w)};
  *(uint4*)(dst + (size_t)z * SIDE + i) = *(uint4*)t;
}

// ---------------- bias convert (fp32 -> bf16, concat, scale z0) -----------
// scale = 1/sqrt(D) * log2(e) so scores feed exp2 directly
__global__ __launch_bounds__(256) void k_cvt_bias(
    const float* s0, const float* s1, const float* s2, const float* s3,
    const float* s4, const float* s5, u16* __restrict__ dst) {
  const float* srcs[6] = {s0, s1, s2, s3, s4, s5};
  int z = blockIdx.y;
  int i = blockIdx.x * 256 + threadIdx.x;
  float sc = (z == 0) ? 0.18033688011112042f : 1.0f;  // 0.125 * log2(e)
  dst[z * 1024 + i] = f2bf(srcs[z][i] * sc);
}

// ---------------- weight transpose fp32 -> bf16, concat, scale z0 ---------
__global__ __launch_bounds__(256) void k_transpose_w(
    const float* a0, const float* a1, const float* a2, const float* a3,
    const float* a4, const float* a5,
    u16* d0, u16* d1, u16* d2, u16* d3, u16* d4, u16* d5) {
  __shared__ u16 tile[64][72];
  const float* srcs[6] = {a0, a1, a2, a3, a4, a5};
  u16* dsts[6] = {d0, d1, d2, d3, d4, d5};
  int z = blockIdx.z;
  float sc = (z == 0) ? 0.18033688011112042f : 1.0f;  // 0.125 * log2(e)
  const float* src = srcs[z] + (size_t)(blockIdx.y * 64) * 1024 + blockIdx.x * 64;
  int t = threadIdx.x;
  int row = t >> 2, c4 = t & 3;
#pragma unroll
  for (int p = 0; p < 2; ++p) {
    int col = c4 * 8 + p * 32;
    const float* sf = src + (size_t)row * 1024 + col;
    float4 x0 = *(const float4*)sf;
    float4 x1 = *(const float4*)(sf + 4);
    u16 tmp[8] = {f2bf(x0.x * sc), f2bf(x0.y * sc), f2bf(x0.z * sc), f2bf(x0.w * sc),
                  f2bf(x1.x * sc), f2bf(x1.y * sc), f2bf(x1.z * sc), f2bf(x1.w * sc)};
    *(uint4*)(&tile[row][col]) = *(uint4*)tmp;
  }
  __syncthreads();
  u16* dst = dsts[z] + (size_t)(blockIdx.x * 64) * 1024 + blockIdx.y * 64;
#pragma unroll
  for (int p = 0; p < 2; ++p) {
    int col = c4 * 8 + p * 32;
    u16 tmp[8];
#pragma unroll
    for (int i = 0; i < 8; ++i) tmp[i] = tile[col + i][row];
    *(uint4*)(dst + (size_t)row * 1024 + col) = *(uint4*)tmp;
  }
}

// ---------------- QKV projection: [4096,1024]bf16 @ WtAB[2048,1024]^T -----
// BK=64 (16 barrier-windows instead of 32); [128][64] LDS tiles staged with
// XOR-granule swizzle (inverse-swizzled global source + swizzled read) to
// break the 128B-row-stride 16-way bank conflict.
__global__ __launch_bounds__(256) void k_gemm_qkv(
    const u16* __restrict__ Aall, const u16* __restrict__ WtA,
    const u16* __restrict__ WtB, const u16* __restrict__ bias,
    u16* __restrict__ qkbuf, u16* __restrict__ vbuf) {
  __shared__ u16 Sh[16384];   // As [128][64] + Bs [128][64] = 32KB
  u16* As = Sh;
  u16* Bs = Sh + 8192;
  int tid = threadIdx.x;
  int wave = tid >> 6, lane = tid & 63;
  int quad = lane >> 4, lrow = lane & 15;
  int wr = wave >> 1, wc = wave & 1;
  int z = blockIdx.z;
  int m0 = blockIdx.y * 128, n0 = blockIdx.x * 128;
  const u16* A = Aall + (size_t)z * SIDE;
  const u16* Wt = z ? WtB : WtA;
  const u16* bi = bias + (size_t)z * 2048;

  f32x4 acc[4][4] = {};
  int srow = 32 * wave + (lane >> 3);        // 8 lanes per 64-col row
  int sgr = lane & 7;                        // granule 0..7
  int ssw = (sgr ^ (lane >> 3)) * 8;         // inverse-swizzled source col
  const u16* gA = A + (size_t)(m0 + srow) * 1024 + ssw;
  const u16* gB = Wt + (size_t)(n0 + srow) * 1024 + ssw;
  u16* lA = &As[(32 * wave) * 64];
  u16* lB = &Bs[(32 * wave) * 64];

  for (int k0 = 0; k0 < 1024; k0 += 64) {
    __syncthreads();
#pragma unroll
    for (int j = 0; j < 4; ++j) {
      __builtin_amdgcn_global_load_lds((gbl_void*)(gA + (size_t)(8 * j) * 1024 + k0),
                                       (lds_void*)(lA + 8 * j * 64), 16, 0, 0);
      __builtin_amdgcn_global_load_lds((gbl_void*)(gB + (size_t)(8 * j) * 1024 + k0),
                                       (lds_void*)(lB + 8 * j * 64), 16, 0, 0);
    }
    __syncthreads();
#pragma unroll
    for (int kk = 0; kk < 2; ++kk) {
      int gq = ((kk << 2) + quad) ^ (lrow & 7);  // swizzled read granule
      bf16x8 af[4], bfr[4];
#pragma unroll
      for (int i = 0; i < 4; ++i)
        af[i] = *(const bf16x8*)&As[(64 * wr + 16 * i + lrow) * 64 + gq * 8];
#pragma unroll
      for (int j = 0; j < 4; ++j)
        bfr[j] = *(const bf16x8*)&Bs[(64 * wc + 16 * j + lrow) * 64 + gq * 8];
#pragma unroll
      for (int i = 0; i < 4; ++i)
#pragma unroll
        for (int j = 0; j < 4; ++j)
          acc[i][j] = __builtin_amdgcn_mfma_f32_16x16x32_bf16(af[i], bfr[j], acc[i][j], 0, 0, 0);
    }
  }

  float bv[4];
#pragma unroll
  for (int j = 0; j < 4; ++j) bv[j] = bf2f(bi[n0 + 64 * wc + 16 * j + lrow]);

  int x = blockIdx.x;
  bool isv = (x >= 8);
  int h = (isv ? 2 * (x - 8) : 2 * x) + wc;
  u16* dst = (isv ? vbuf : qkbuf) + (size_t)z * SIDE;
  u16* lw = Sh + wave * 1216;  // 16 rows * stride 76 per wave

  __syncthreads();  // all waves done reading As/Bs
#pragma unroll
  for (int i = 0; i < 4; ++i) {
#pragma unroll
    for (int j = 0; j < 4; ++j)
#pragma unroll
      for (int r = 0; r < 4; ++r)
        lw[(4 * quad + r) * 76 + 16 * j + lrow] = f2bf(acc[i][j][r] + bv[j]);
    asm volatile("s_waitcnt lgkmcnt(0)" ::: "memory");
    int row = lane >> 2, cg = (lane & 3) * 16;
    int rg = m0 + 64 * wr + 16 * i + row;
    int bb = rg >> 11, rl = rg & 2047;
    u16* dr = dst + (size_t)(bb * 16 + h) * BHSTR + (size_t)rl * 64 + cg;
    uint2 w0 = *(const uint2*)&lw[row * 76 + cg];
    uint2 w1 = *(const uint2*)&lw[row * 76 + cg + 4];
    uint2 w2 = *(const uint2*)&lw[row * 76 + cg + 8];
    uint2 w3 = *(const uint2*)&lw[row * 76 + cg + 12];
    uint4 o0 = {w0.x, w0.y, w1.x, w1.y};
    uint4 o1 = {w2.x, w2.y, w3.x, w3.y};
    *(uint4*)dr = o0;
    *(uint4*)(dr + 8) = o1;
    asm volatile("s_waitcnt lgkmcnt(0)" ::: "memory");  // WAR fence before next pass
  }
}

// ---------------- V transpose per head: [sbh][2048][64] -> [sbh][64][2048] --
__global__ __launch_bounds__(256) void k_transpose_v(const u16* __restrict__ v,
                                                     u16* __restrict__ vt) {
  __shared__ u16 tile[64][72];
  int sbh = blockIdx.y;
  int n0 = blockIdx.x * 64;
  const u16* src = v + (size_t)sbh * BHSTR + (size_t)n0 * 64;
  u16* dst = vt + (size_t)sbh * BHSTR + n0;
  int t = threadIdx.x;
  int row = t >> 2, c4 = t & 3;
#pragma unroll
  for (int p = 0; p < 2; ++p) {
    int col = c4 * 8 + p * 32;
    uint4 q = *(const uint4*)(src + (size_t)row * 64 + col);
    *(uint4*)(&tile[row][col]) = q;
  }
  __syncthreads();
#pragma unroll
  for (int p = 0; p < 2; ++p) {
    int col = c4 * 8 + p * 32;
    u16 tmp[8];
#pragma unroll
    for (int i = 0; i < 8; ++i) tmp[i] = tile[col + i][row];
    *(uint4*)(dst + (size_t)row * 2048 + col) = *(uint4*)tmp;
  }
}

// ---------------- fused dual-softmax attention, both sides ----------------
// z=0: Q=aq,K=bq,V=bv -> a_ctx ; z=1: Q=bq,K=aq,V=av -> b_ctx
// REVERT to the hardware-proven r0 structure (119.0 us): S^T via A=K,B=Q;
// Ps packed b64 writes, swizzled, b128 A-frag reads; double-buffered K/V
// with __syncthreads; shuffle-reduce rinv epilogue.  Only delta vs r0:
// exp2f with log2(e) pre-folded into Wa_qk/ba_qk (verified passing r2/r3).
__global__ __launch_bounds__(256) void k_attn(
    const u16* __restrict__ qk, const u16* __restrict__ vt,
    u16* __restrict__ ctx) {
  __shared__ u16 Ks[2 * 4096];
  __shared__ u16 Vs[2 * 4096];
  __shared__ u16 Ps[128 * 64];  // Q staging, then P tiles (wave-private rows)
  int tid = threadIdx.x;
  int wave = tid >> 6, lane = tid & 63;
  int quad = lane >> 4, lrow = lane & 15;
  int z = blockIdx.z, bh = blockIdx.x;      // x=bh: l-tiles of one (z,bh) share an XCD
  int l0 = blockIdx.y * 128;
  const u16* Qb = qk + (size_t)z * SIDE + (size_t)bh * BHSTR + (size_t)l0 * 64;
  const u16* Kb = qk + (size_t)(1 - z) * SIDE + (size_t)bh * BHSTR;
  const u16* Vtb = vt + (size_t)(1 - z) * SIDE + (size_t)bh * BHSTR;

  // stage Q (granule-swizzled); wave w stages exactly its own rows 32w..32w+31
#pragma unroll
  for (int p = 0; p < 4; ++p) {
    int G0 = wave * 256 + p * 64;
    int G = G0 + lane;
    int row = G >> 3, c = G & 7;
    __builtin_amdgcn_global_load_lds((gbl_void*)(Qb + (size_t)row * 64 + ((c ^ (row & 7)) * 8)),
                                     (lds_void*)(Ps + G0 * 8), 16, 0, 0);
  }
  // stage K/V round 0 into buffer 0
#pragma unroll
  for (int p = 0; p < 2; ++p) {
    int G0 = p * 256 + wave * 64;
    int G = G0 + lane;
    int row = G >> 3, c = G & 7;
    int sw = (c ^ (row & 7)) * 8;
    __builtin_amdgcn_global_load_lds((gbl_void*)(Kb + (size_t)row * 64 + sw),
                                     (lds_void*)(Ks + G0 * 8), 16, 0, 0);
    __builtin_amdgcn_global_load_lds((gbl_void*)(Vtb + (size_t)row * 2048 + sw),
                                     (lds_void*)(Vs + G0 * 8), 16, 0, 0);
  }

  bf16x8 qf[2][2];
  f32x4 cacc[2][4] = {};
  float rsum[2] = {0.f, 0.f};
  int e = 2 * (lrow & 7);

  for (int it = 0; it < 32; ++it) {
    __syncthreads();  // vmcnt(0)+barrier: prev-issued DMAs (overlapped) now visible
    if (it == 0) {
#pragma unroll
      for (int rt = 0; rt < 2; ++rt) {
        int lq = 32 * wave + 16 * rt + lrow;
        qf[rt][0] = *(const bf16x8*)&Ps[(lq * 8 + (quad ^ (lq & 7))) * 8];
        qf[rt][1] = *(const bf16x8*)&Ps[(lq * 8 + ((quad + 4) ^ (lq & 7))) * 8];
      }
    }
    int prty = it & 1;
    if (it + 1 < 32) {  // prefetch next round into other buffer
      int s1 = (it + 1) << 6;
      int nb = (1 - prty) * 4096;
#pragma unroll
      for (int p = 0; p < 2; ++p) {
        int G0 = p * 256 + wave * 64;
        int G = G0 + lane;
        int row = G >> 3, c = G & 7;
        int sw = (c ^ (row & 7)) * 8;
        __builtin_amdgcn_global_load_lds((gbl_void*)(Kb + (size_t)(s1 + row) * 64 + sw),
                                         (lds_void*)(Ks + nb + G0 * 8), 16, 0, 0);
        __builtin_amdgcn_global_load_lds((gbl_void*)(Vtb + (size_t)row * 2048 + s1 + sw),
                                         (lds_void*)(Vs + nb + G0 * 8), 16, 0, 0);
      }
    }
    const u16* KsC = Ks + prty * 4096;
    const u16* VsC = Vs + prty * 4096;
    // S^T = K·Q^T (scale+log2e pre-folded), exp2, packed b64 -> Ps (l-major, swizzled)
#pragma unroll
    for (int j = 0; j < 4; ++j) {
      int kr = 16 * j + lrow;
      bf16x8 kf0 = *(const bf16x8*)&KsC[(kr * 8 + (quad ^ (kr & 7))) * 8];
      bf16x8 kf1 = *(const bf16x8*)&KsC[(kr * 8 + ((quad + 4) ^ (kr & 7))) * 8];
#pragma unroll
      for (int rt = 0; rt < 2; ++rt) {
        f32x4 s = {};
        s = __builtin_amdgcn_mfma_f32_16x16x32_bf16(kf0, qf[rt][0], s, 0, 0, 0);
        s = __builtin_amdgcn_mfma_f32_16x16x32_bf16(kf1, qf[rt][1], s, 0, 0, 0);
        float e0 = exp2f(s[0]), e1 = exp2f(s[1]);
        float e2 = exp2f(s[2]), e3 = exp2f(s[3]);
        rsum[rt] += (e0 + e1) + (e2 + e3);
        uint2 pk;
        pk.x = ((u32)f2bf(e1) << 16) | (u32)f2bf(e0);
        pk.y = ((u32)f2bf(e3) << 16) | (u32)f2bf(e2);
        *(uint2*)&Ps[(32 * wave + 16 * rt + lrow) * 64 + ((4 * j + quad) ^ e) * 4] = pk;
      }
    }
    asm volatile("s_waitcnt lgkmcnt(0)" ::: "memory");  // wave-private Ps round-trip
    bf16x8 pf[2][2];
#pragma unroll
    for (int rt = 0; rt < 2; ++rt) {
      const u16* pr = &Ps[(32 * wave + 16 * rt + lrow) * 64];
      pf[rt][0] = *(const bf16x8*)&pr[((2 * quad) ^ e) * 4];
      pf[rt][1] = *(const bf16x8*)&pr[((2 * quad + 8) ^ e) * 4];
    }
    // P @ V
#pragma unroll
    for (int j = 0; j < 4; ++j) {
      int vr = 16 * j + lrow;
      bf16x8 vf0 = *(const bf16x8*)&VsC[(vr * 8 + (quad ^ (vr & 7))) * 8];
      bf16x8 vf1 = *(const bf16x8*)&VsC[(vr * 8 + ((quad + 4) ^ (vr & 7))) * 8];
#pragma unroll
      for (int rt = 0; rt < 2; ++rt) {
        cacc[rt][j] = __builtin_amdgcn_mfma_f32_16x16x32_bf16(pf[rt][0], vf0, cacc[rt][j], 0, 0, 0);
        cacc[rt][j] = __builtin_amdgcn_mfma_f32_16x16x32_bf16(pf[rt][1], vf1, cacc[rt][j], 0, 0, 0);
      }
    }
  }

  float rinv[2][4];
#pragma unroll
  for (int rt = 0; rt < 2; ++rt) {
    float v = rsum[rt];
    v += __shfl_xor(v, 16);
    v += __shfl_xor(v, 32);
    float rv = 1.0f / v;
#pragma unroll
    for (int r = 0; r < 4; ++r)
      rinv[rt][r] = __shfl(rv, 20 * quad + r);  // total for l_local = 4*quad + r
  }

  int bb = bh >> 4, h = bh & 15;
  u16* Ob = ctx + (size_t)z * SIDE + (size_t)(bb * 2048 + l0) * 1024 + h * 64;
#pragma unroll
  for (int rt = 0; rt < 2; ++rt)
#pragma unroll
    for (int r = 0; r < 4; ++r) {
      int l = 32 * wave + 16 * rt + 4 * quad + r;
#pragma unroll
      for (int j = 0; j < 4; ++j)
        Ob[(size_t)l * 1024 + 16 * j + lrow] = f2bf(cacc[rt][j][r] * rinv[rt][r]);
    }
}

// ---------------- O projection: ctx[4096,1024]bf16 @ WtO^T + bias -> fp32 --
// BK=64, same swizzled staging as k_gemm_qkv.
__global__ __launch_bounds__(256) void k_gemm_o(
    const u16* __restrict__ ctx, const u16* __restrict__ WtO,
    const u16* __restrict__ bias, float* __restrict__ out) {
  __shared__ u16 As[128 * 64];
  __shared__ u16 Bs[128 * 64];
  int tid = threadIdx.x;
  int wave = tid >> 6, lane = tid & 63;
  int quad = lane >> 4, lrow = lane & 15;
  int wr = wave >> 1, wc = wave & 1;
  int z = blockIdx.z;
  int m0 = blockIdx.y * 128, n0 = blockIdx.x * 128;
  const u16* A = ctx + (size_t)z * SIDE;
  const u16* Wt = WtO + (size_t)z * 1048576;
  const u16* bi = bias + (size_t)z * 1024;
  float* C = out + (size_t)z * SIDE;

  f32x4 acc[4][4] = {};
  int srow = 32 * wave + (lane >> 3);
  int ssw = ((lane & 7) ^ (lane >> 3)) * 8;
  const u16* gA = A + (size_t)(m0 + srow) * 1024 + ssw;
  const u16* gB = Wt + (size_t)(n0 + srow) * 1024 + ssw;
  u16* lA = &As[(32 * wave) * 64];
  u16* lB = &Bs[(32 * wave) * 64];

  for (int k0 = 0; k0 < 1024; k0 += 64) {
    __syncthreads();
#pragma unroll
    for (int j = 0; j < 4; ++j) {
      __builtin_amdgcn_global_load_lds((gbl_void*)(gA + (size_t)(8 * j) * 1024 + k0),
                                       (lds_void*)(lA + 8 * j * 64), 16, 0, 0);
      __builtin_amdgcn_global_load_lds((gbl_void*)(gB + (size_t)(8 * j) * 1024 + k0),
                                       (lds_void*)(lB + 8 * j * 64), 16, 0, 0);
    }
    __syncthreads();
#pragma unroll
    for (int kk = 0; kk < 2; ++kk) {
      int gq = ((kk << 2) + quad) ^ (lrow & 7);
      bf16x8 af[4], bfr[4];
#pragma unroll
      for (int i = 0; i < 4; ++i)
        af[i] = *(const bf16x8*)&As[(64 * wr + 16 * i + lrow) * 64 + gq * 8];
#pragma unroll
      for (int j = 0; j < 4; ++j)
        bfr[j] = *(const bf16x8*)&Bs[(64 * wc + 16 * j + lrow) * 64 + gq * 8];
#pragma unroll
      for (int i = 0; i < 4; ++i)
#pragma unroll
        for (int j = 0; j < 4; ++j)
          acc[i][j] = __builtin_amdgcn_mfma_f32_16x16x32_bf16(af[i], bfr[j], acc[i][j], 0, 0, 0);
    }
  }

  float bv[4];
#pragma unroll
  for (int j = 0; j < 4; ++j) bv[j] = bf2f(bi[n0 + 64 * wc + 16 * j + lrow]);
#pragma unroll
  for (int i = 0; i < 4; ++i) {
    int row = m0 + 64 * wr + 16 * i + 4 * quad;
#pragma unroll
    for (int j = 0; j < 4; ++j) {
      int col = n0 + 64 * wc + 16 * j + lrow;
#pragma unroll
      for (int r = 0; r < 4; ++r)
        C[(size_t)(row + r) * 1024 + col] = acc[i][j][r] + bv[j];
    }
  }
}

extern "C" void kernel_launch(void* const* d_in, const int* in_sizes, int n_in,
                              void* d_out, int out_size, void* d_ws, size_t ws_size,
                              hipStream_t stream) {
  (void)in_sizes; (void)n_in; (void)out_size; (void)ws_size;
  const size_t M1 = 1048576u;
  u16* ws = (u16*)d_ws;
  u16* wtA   = ws;             // [2048,1024] concat(Wa_qk^T*0.125*log2e, Wa_v^T)
  u16* wtB   = ws + 2 * M1;    // [2048,1024] concat(Wb_qk^T, Wb_v^T)
  u16* wtO   = ws + 4 * M1;    // [2048,1024] concat(Wa_o^T, Wb_o^T)
  u16* biasQ = ws + 6 * M1;    // [2,2048]
  u16* biasO = ws + 6 * M1 + 4096;  // [2,1024]
  u16* ab    = ws + 7 * M1;    // [2][4096,1024] bf16 inputs (dead after QKV)
  u16* vt    = ab;             // alias: [2][bh][64][2048]
  u16* qkbuf = ws + 15 * M1;   // [2][bh][2048][64]
  u16* vbuf  = ws + 23 * M1;   // [2][bh][2048][64] (dead after transpose_v)
  u16* ctx   = vbuf;           // alias: [2][4096,1024]

  dim3 blk(256);
  k_cvt_in<<<dim3(2048, 2), blk, 0, stream>>>((const float*)d_in[0],
                                              (const float*)d_in[1], ab);
  k_cvt_bias<<<dim3(4, 6), blk, 0, stream>>>(
      (const float*)d_in[3], (const float*)d_in[5], (const float*)d_in[7],
      (const float*)d_in[9], (const float*)d_in[11], (const float*)d_in[13], biasQ);
  k_transpose_w<<<dim3(16, 16, 6), blk, 0, stream>>>(
      (const float*)d_in[2], (const float*)d_in[4], (const float*)d_in[6],
      (const float*)d_in[8], (const float*)d_in[10], (const float*)d_in[12],
      wtA, wtA + M1, wtB, wtB + M1, wtO, wtO + M1);
  k_gemm_qkv<<<dim3(16, 32, 2), blk, 0, stream>>>(ab, wtA, wtB, biasQ, qkbuf, vbuf);
  k_transpose_v<<<dim3(32, 64), blk, 0, stream>>>(vbuf, vt);
  k_attn<<<dim3(32, 16, 2), blk, 0, stream>>>(qkbuf, vt, ctx);
  k_gemm_o<<<dim3(8, 32, 2), blk, 0, stream>>>(ctx, wtO, biasO, (float*)d_out);
}

// Round 8
// 295.260 us; speedup vs baseline: 1.0909x; 1.0871x over previous
//
#include <hip/hip_runtime.h>
#include <hip/hip_bf16.h>
#include <stdint.h>

typedef unsigned short u16;
typedef unsigned int u32;
typedef __attribute__((ext_vector_type(8))) short bf16x8;
typedef __attribute__((ext_vector_type(4))) float f32x4;

typedef __attribute__((address_space(3))) void lds_void;
typedef const __attribute__((address_space(1))) void gbl_void;

#define SIDE 4194304u   // 4M elems = one side's [B,H,2048,64] / [4096,1024]
#define BHSTR 131072u   // 2048*64 per (b,h)

static __device__ __forceinline__ u16 f2bf(float f) {
  union { __hip_bfloat16 b; u16 u; } cv;
  cv.b = __float2bfloat16(f);
  return cv.u;
}
static __device__ __forceinline__ float bf2f(u16 u) {
  union { __hip_bfloat16 b; u16 u; } cv;
  cv.u = u;
  return __bfloat162float(cv.b);
}

// raw v_exp_f32 (1 VALU op, 1 ULP): input already scaled by log2(e)
static __device__ __forceinline__ float fast_exp2(float x) {
#if __has_builtin(__builtin_amdgcn_exp2f)
  return __builtin_amdgcn_exp2f(x);
#else
  float r;
  asm("v_exp_f32 %0, %1" : "=v"(r) : "v"(x));
  return r;
#endif
}

// ---------------- input convert: a,b fp32 -> bf16 row-major ----------------
__global__ __launch_bounds__(256) void k_cvt_in(const float* __restrict__ a,
                                                const float* __restrict__ b,
                                                u16* __restrict__ dst) {
  int z = blockIdx.y;
  const float* src = z ? b : a;
  size_t i = ((size_t)blockIdx.x * 256 + threadIdx.x) * 8;
  float4 x0 = *(const float4*)(src + i);
  float4 x1 = *(const float4*)(src + i + 4);
  u16 t[8] = {f2bf(x0.x), f2bf(x0.y), f2bf(x0.z), f2bf(x0.w),
              f2bf(x1.x), f2bf(x1.y), f2bf(x1.z), f2bf(x1.w)};
  *(uint4*)(dst + (size_t)z * SIDE + i) = *(uint4*)t;
}

// ---------------- bias convert (fp32 -> bf16, concat, scale z0) -----------
// scale = 1/sqrt(D) * log2(e) so scores feed raw v_exp_f32 directly
__global__ __launch_bounds__(256) void k_cvt_bias(
    const float* s0, const float* s1, const float* s2, const float* s3,
    const float* s4, const float* s5, u16* __restrict__ dst) {
  const float* srcs[6] = {s0, s1, s2, s3, s4, s5};
  int z = blockIdx.y;
  int i = blockIdx.x * 256 + threadIdx.x;
  float sc = (z == 0) ? 0.18033688011112042f : 1.0f;  // 0.125 * log2(e)
  dst[z * 1024 + i] = f2bf(srcs[z][i] * sc);
}

// ---------------- weight transpose fp32 -> bf16, concat, scale z0 ---------
__global__ __launch_bounds__(256) void k_transpose_w(
    const float* a0, const float* a1, const float* a2, const float* a3,
    const float* a4, const float* a5,
    u16* d0, u16* d1, u16* d2, u16* d3, u16* d4, u16* d5) {
  __shared__ u16 tile[64][72];
  const float* srcs[6] = {a0, a1, a2, a3, a4, a5};
  u16* dsts[6] = {d0, d1, d2, d3, d4, d5};
  int z = blockIdx.z;
  float sc = (z == 0) ? 0.18033688011112042f : 1.0f;  // 0.125 * log2(e)
  const float* src = srcs[z] + (size_t)(blockIdx.y * 64) * 1024 + blockIdx.x * 64;
  int t = threadIdx.x;
  int row = t >> 2, c4 = t & 3;
#pragma unroll
  for (int p = 0; p < 2; ++p) {
    int col = c4 * 8 + p * 32;
    const float* sf = src + (size_t)row * 1024 + col;
    float4 x0 = *(const float4*)sf;
    float4 x1 = *(const float4*)(sf + 4);
    u16 tmp[8] = {f2bf(x0.x * sc), f2bf(x0.y * sc), f2bf(x0.z * sc), f2bf(x0.w * sc),
                  f2bf(x1.x * sc), f2bf(x1.y * sc), f2bf(x1.z * sc), f2bf(x1.w * sc)};
    *(uint4*)(&tile[row][col]) = *(uint4*)tmp;
  }
  __syncthreads();
  u16* dst = dsts[z] + (size_t)(blockIdx.x * 64) * 1024 + blockIdx.y * 64;
#pragma unroll
  for (int p = 0; p < 2; ++p) {
    int col = c4 * 8 + p * 32;
    u16 tmp[8];
#pragma unroll
    for (int i = 0; i < 8; ++i) tmp[i] = tile[col + i][row];
    *(uint4*)(dst + (size_t)row * 1024 + col) = *(uint4*)tmp;
  }
}

// ---------------- QKV projection: [4096,1024]bf16 @ WtAB[2048,1024]^T -----
// BK=64 (16 barrier-windows instead of 32); [128][64] LDS tiles staged with
// XOR-granule swizzle (inverse-swizzled global source + swizzled read) to
// break the 128B-row-stride 16-way bank conflict.
__global__ __launch_bounds__(256) void k_gemm_qkv(
    const u16* __restrict__ Aall, const u16* __restrict__ WtA,
    const u16* __restrict__ WtB, const u16* __restrict__ bias,
    u16* __restrict__ qkbuf, u16* __restrict__ vbuf) {
  __shared__ u16 Sh[16384];   // As [128][64] + Bs [128][64] = 32KB
  u16* As = Sh;
  u16* Bs = Sh + 8192;
  int tid = threadIdx.x;
  int wave = tid >> 6, lane = tid & 63;
  int quad = lane >> 4, lrow = lane & 15;
  int wr = wave >> 1, wc = wave & 1;
  int z = blockIdx.z;
  int m0 = blockIdx.y * 128, n0 = blockIdx.x * 128;
  const u16* A = Aall + (size_t)z * SIDE;
  const u16* Wt = z ? WtB : WtA;
  const u16* bi = bias + (size_t)z * 2048;

  f32x4 acc[4][4] = {};
  int srow = 32 * wave + (lane >> 3);        // 8 lanes per 64-col row
  int sgr = lane & 7;                        // granule 0..7
  int ssw = (sgr ^ (lane >> 3)) * 8;         // inverse-swizzled source col
  const u16* gA = A + (size_t)(m0 + srow) * 1024 + ssw;
  const u16* gB = Wt + (size_t)(n0 + srow) * 1024 + ssw;
  u16* lA = &As[(32 * wave) * 64];
  u16* lB = &Bs[(32 * wave) * 64];

  for (int k0 = 0; k0 < 1024; k0 += 64) {
    __syncthreads();
#pragma unroll
    for (int j = 0; j < 4; ++j) {
      __builtin_amdgcn_global_load_lds((gbl_void*)(gA + (size_t)(8 * j) * 1024 + k0),
                                       (lds_void*)(lA + 8 * j * 64), 16, 0, 0);
      __builtin_amdgcn_global_load_lds((gbl_void*)(gB + (size_t)(8 * j) * 1024 + k0),
                                       (lds_void*)(lB + 8 * j * 64), 16, 0, 0);
    }
    __syncthreads();
#pragma unroll
    for (int kk = 0; kk < 2; ++kk) {
      int gq = ((kk << 2) + quad) ^ (lrow & 7);  // swizzled read granule
      bf16x8 af[4], bfr[4];
#pragma unroll
      for (int i = 0; i < 4; ++i)
        af[i] = *(const bf16x8*)&As[(64 * wr + 16 * i + lrow) * 64 + gq * 8];
#pragma unroll
      for (int j = 0; j < 4; ++j)
        bfr[j] = *(const bf16x8*)&Bs[(64 * wc + 16 * j + lrow) * 64 + gq * 8];
#pragma unroll
      for (int i = 0; i < 4; ++i)
#pragma unroll
        for (int j = 0; j < 4; ++j)
          acc[i][j] = __builtin_amdgcn_mfma_f32_16x16x32_bf16(af[i], bfr[j], acc[i][j], 0, 0, 0);
    }
  }

  float bv[4];
#pragma unroll
  for (int j = 0; j < 4; ++j) bv[j] = bf2f(bi[n0 + 64 * wc + 16 * j + lrow]);

  int x = blockIdx.x;
  bool isv = (x >= 8);
  int h = (isv ? 2 * (x - 8) : 2 * x) + wc;
  u16* dst = (isv ? vbuf : qkbuf) + (size_t)z * SIDE;
  u16* lw = Sh + wave * 1216;  // 16 rows * stride 76 per wave

  __syncthreads();  // all waves done reading As/Bs
#pragma unroll
  for (int i = 0; i < 4; ++i) {
#pragma unroll
    for (int j = 0; j < 4; ++j)
#pragma unroll
      for (int r = 0; r < 4; ++r)
        lw[(4 * quad + r) * 76 + 16 * j + lrow] = f2bf(acc[i][j][r] + bv[j]);
    asm volatile("s_waitcnt lgkmcnt(0)" ::: "memory");
    int row = lane >> 2, cg = (lane & 3) * 16;
    int rg = m0 + 64 * wr + 16 * i + row;
    int bb = rg >> 11, rl = rg & 2047;
    u16* dr = dst + (size_t)(bb * 16 + h) * BHSTR + (size_t)rl * 64 + cg;
    uint2 w0 = *(const uint2*)&lw[row * 76 + cg];
    uint2 w1 = *(const uint2*)&lw[row * 76 + cg + 4];
    uint2 w2 = *(const uint2*)&lw[row * 76 + cg + 8];
    uint2 w3 = *(const uint2*)&lw[row * 76 + cg + 12];
    uint4 o0 = {w0.x, w0.y, w1.x, w1.y};
    uint4 o1 = {w2.x, w2.y, w3.x, w3.y};
    *(uint4*)dr = o0;
    *(uint4*)(dr + 8) = o1;
    asm volatile("s_waitcnt lgkmcnt(0)" ::: "memory");  // WAR fence before next pass
  }
}

// ---------------- V transpose per head: [sbh][2048][64] -> [sbh][64][2048] --
__global__ __launch_bounds__(256) void k_transpose_v(const u16* __restrict__ v,
                                                     u16* __restrict__ vt) {
  __shared__ u16 tile[64][72];
  int sbh = blockIdx.y;
  int n0 = blockIdx.x * 64;
  const u16* src = v + (size_t)sbh * BHSTR + (size_t)n0 * 64;
  u16* dst = vt + (size_t)sbh * BHSTR + n0;
  int t = threadIdx.x;
  int row = t >> 2, c4 = t & 3;
#pragma unroll
  for (int p = 0; p < 2; ++p) {
    int col = c4 * 8 + p * 32;
    uint4 q = *(const uint4*)(src + (size_t)row * 64 + col);
    *(uint4*)(&tile[row][col]) = q;
  }
  __syncthreads();
#pragma unroll
  for (int p = 0; p < 2; ++p) {
    int col = c4 * 8 + p * 32;
    u16 tmp[8];
#pragma unroll
    for (int i = 0; i < 8; ++i) tmp[i] = tile[col + i][row];
    *(uint4*)(dst + (size_t)row * 2048 + col) = *(uint4*)tmp;
  }
}

// ---------------- fused dual-softmax attention, both sides ----------------
// z=0: Q=aq,K=bq,V=bv -> a_ctx ; z=1: Q=bq,K=aq,V=av -> b_ctx
// Hardware-proven r0 structure; only delta: raw v_exp_f32 (log2e pre-folded
// into Wa_qk/ba_qk) replaces __expf — 1 VALU op per exp instead of 2
// (and instead of exp2f's ~10-op correctly-rounded OCML path, the r7 bug).
__global__ __launch_bounds__(256) void k_attn(
    const u16* __restrict__ qk, const u16* __restrict__ vt,
    u16* __restrict__ ctx) {
  __shared__ u16 Ks[2 * 4096];
  __shared__ u16 Vs[2 * 4096];
  __shared__ u16 Ps[128 * 64];  // Q staging, then P tiles (wave-private rows)
  int tid = threadIdx.x;
  int wave = tid >> 6, lane = tid & 63;
  int quad = lane >> 4, lrow = lane & 15;
  int z = blockIdx.z, bh = blockIdx.x;      // x=bh: l-tiles of one (z,bh) share an XCD
  int l0 = blockIdx.y * 128;
  const u16* Qb = qk + (size_t)z * SIDE + (size_t)bh * BHSTR + (size_t)l0 * 64;
  const u16* Kb = qk + (size_t)(1 - z) * SIDE + (size_t)bh * BHSTR;
  const u16* Vtb = vt + (size_t)(1 - z) * SIDE + (size_t)bh * BHSTR;

  // stage Q (granule-swizzled); wave w stages exactly its own rows 32w..32w+31
#pragma unroll
  for (int p = 0; p < 4; ++p) {
    int G0 = wave * 256 + p * 64;
    int G = G0 + lane;
    int row = G >> 3, c = G & 7;
    __builtin_amdgcn_global_load_lds((gbl_void*)(Qb + (size_t)row * 64 + ((c ^ (row & 7)) * 8)),
                                     (lds_void*)(Ps + G0 * 8), 16, 0, 0);
  }
  // stage K/V round 0 into buffer 0
#pragma unroll
  for (int p = 0; p < 2; ++p) {
    int G0 = p * 256 + wave * 64;
    int G = G0 + lane;
    int row = G >> 3, c = G & 7;
    int sw = (c ^ (row & 7)) * 8;
    __builtin_amdgcn_global_load_lds((gbl_void*)(Kb + (size_t)row * 64 + sw),
                                     (lds_void*)(Ks + G0 * 8), 16, 0, 0);
    __builtin_amdgcn_global_load_lds((gbl_void*)(Vtb + (size_t)row * 2048 + sw),
                                     (lds_void*)(Vs + G0 * 8), 16, 0, 0);
  }

  bf16x8 qf[2][2];
  f32x4 cacc[2][4] = {};
  float rsum[2] = {0.f, 0.f};
  int e = 2 * (lrow & 7);

  for (int it = 0; it < 32; ++it) {
    __syncthreads();  // vmcnt(0)+barrier: prev-issued DMAs (overlapped) now visible
    if (it == 0) {
#pragma unroll
      for (int rt = 0; rt < 2; ++rt) {
        int lq = 32 * wave + 16 * rt + lrow;
        qf[rt][0] = *(const bf16x8*)&Ps[(lq * 8 + (quad ^ (lq & 7))) * 8];
        qf[rt][1] = *(const bf16x8*)&Ps[(lq * 8 + ((quad + 4) ^ (lq & 7))) * 8];
      }
    }
    int prty = it & 1;
    if (it + 1 < 32) {  // prefetch next round into other buffer
      int s1 = (it + 1) << 6;
      int nb = (1 - prty) * 4096;
#pragma unroll
      for (int p = 0; p < 2; ++p) {
        int G0 = p * 256 + wave * 64;
        int G = G0 + lane;
        int row = G >> 3, c = G & 7;
        int sw = (c ^ (row & 7)) * 8;
        __builtin_amdgcn_global_load_lds((gbl_void*)(Kb + (size_t)(s1 + row) * 64 + sw),
                                         (lds_void*)(Ks + nb + G0 * 8), 16, 0, 0);
        __builtin_amdgcn_global_load_lds((gbl_void*)(Vtb + (size_t)row * 2048 + s1 + sw),
                                         (lds_void*)(Vs + nb + G0 * 8), 16, 0, 0);
      }
    }
    const u16* KsC = Ks + prty * 4096;
    const u16* VsC = Vs + prty * 4096;
    // S^T = K·Q^T (scale+log2e pre-folded), v_exp, packed b64 -> Ps (swizzled)
#pragma unroll
    for (int j = 0; j < 4; ++j) {
      int kr = 16 * j + lrow;
      bf16x8 kf0 = *(const bf16x8*)&KsC[(kr * 8 + (quad ^ (kr & 7))) * 8];
      bf16x8 kf1 = *(const bf16x8*)&KsC[(kr * 8 + ((quad + 4) ^ (kr & 7))) * 8];
#pragma unroll
      for (int rt = 0; rt < 2; ++rt) {
        f32x4 s = {};
        s = __builtin_amdgcn_mfma_f32_16x16x32_bf16(kf0, qf[rt][0], s, 0, 0, 0);
        s = __builtin_amdgcn_mfma_f32_16x16x32_bf16(kf1, qf[rt][1], s, 0, 0, 0);
        float e0 = fast_exp2(s[0]), e1 = fast_exp2(s[1]);
        float e2 = fast_exp2(s[2]), e3 = fast_exp2(s[3]);
        rsum[rt] += (e0 + e1) + (e2 + e3);
        uint2 pk;
        pk.x = ((u32)f2bf(e1) << 16) | (u32)f2bf(e0);
        pk.y = ((u32)f2bf(e3) << 16) | (u32)f2bf(e2);
        *(uint2*)&Ps[(32 * wave + 16 * rt + lrow) * 64 + ((4 * j + quad) ^ e) * 4] = pk;
      }
    }
    asm volatile("s_waitcnt lgkmcnt(0)" ::: "memory");  // wave-private Ps round-trip
    bf16x8 pf[2][2];
#pragma unroll
    for (int rt = 0; rt < 2; ++rt) {
      const u16* pr = &Ps[(32 * wave + 16 * rt + lrow) * 64];
      pf[rt][0] = *(const bf16x8*)&pr[((2 * quad) ^ e) * 4];
      pf[rt][1] = *(const bf16x8*)&pr[((2 * quad + 8) ^ e) * 4];
    }
    // P @ V
#pragma unroll
    for (int j = 0; j < 4; ++j) {
      int vr = 16 * j + lrow;
      bf16x8 vf0 = *(const bf16x8*)&VsC[(vr * 8 + (quad ^ (vr & 7))) * 8];
      bf16x8 vf1 = *(const bf16x8*)&VsC[(vr * 8 + ((quad + 4) ^ (vr & 7))) * 8];
#pragma unroll
      for (int rt = 0; rt < 2; ++rt) {
        cacc[rt][j] = __builtin_amdgcn_mfma_f32_16x16x32_bf16(pf[rt][0], vf0, cacc[rt][j], 0, 0, 0);
        cacc[rt][j] = __builtin_amdgcn_mfma_f32_16x16x32_bf16(pf[rt][1], vf1, cacc[rt][j], 0, 0, 0);
      }
    }
  }

  float rinv[2][4];
#pragma unroll
  for (int rt = 0; rt < 2; ++rt) {
    float v = rsum[rt];
    v += __shfl_xor(v, 16);
    v += __shfl_xor(v, 32);
    float rv = 1.0f / v;
#pragma unroll
    for (int r = 0; r < 4; ++r)
      rinv[rt][r] = __shfl(rv, 20 * quad + r);  // total for l_local = 4*quad + r
  }

  int bb = bh >> 4, h = bh & 15;
  u16* Ob = ctx + (size_t)z * SIDE + (size_t)(bb * 2048 + l0) * 1024 + h * 64;
#pragma unroll
  for (int rt = 0; rt < 2; ++rt)
#pragma unroll
    for (int r = 0; r < 4; ++r) {
      int l = 32 * wave + 16 * rt + 4 * quad + r;
#pragma unroll
      for (int j = 0; j < 4; ++j)
        Ob[(size_t)l * 1024 + 16 * j + lrow] = f2bf(cacc[rt][j][r] * rinv[rt][r]);
    }
}

// ---------------- O projection: ctx[4096,1024]bf16 @ WtO^T + bias -> fp32 --
// BK=64, same swizzled staging as k_gemm_qkv.
__global__ __launch_bounds__(256) void k_gemm_o(
    const u16* __restrict__ ctx, const u16* __restrict__ WtO,
    const u16* __restrict__ bias, float* __restrict__ out) {
  __shared__ u16 As[128 * 64];
  __shared__ u16 Bs[128 * 64];
  int tid = threadIdx.x;
  int wave = tid >> 6, lane = tid & 63;
  int quad = lane >> 4, lrow = lane & 15;
  int wr = wave >> 1, wc = wave & 1;
  int z = blockIdx.z;
  int m0 = blockIdx.y * 128, n0 = blockIdx.x * 128;
  const u16* A = ctx + (size_t)z * SIDE;
  const u16* Wt = WtO + (size_t)z * 1048576;
  const u16* bi = bias + (size_t)z * 1024;
  float* C = out + (size_t)z * SIDE;

  f32x4 acc[4][4] = {};
  int srow = 32 * wave + (lane >> 3);
  int ssw = ((lane & 7) ^ (lane >> 3)) * 8;
  const u16* gA = A + (size_t)(m0 + srow) * 1024 + ssw;
  const u16* gB = Wt + (size_t)(n0 + srow) * 1024 + ssw;
  u16* lA = &As[(32 * wave) * 64];
  u16* lB = &Bs[(32 * wave) * 64];

  for (int k0 = 0; k0 < 1024; k0 += 64) {
    __syncthreads();
#pragma unroll
    for (int j = 0; j < 4; ++j) {
      __builtin_amdgcn_global_load_lds((gbl_void*)(gA + (size_t)(8 * j) * 1024 + k0),
                                       (lds_void*)(lA + 8 * j * 64), 16, 0, 0);
      __builtin_amdgcn_global_load_lds((gbl_void*)(gB + (size_t)(8 * j) * 1024 + k0),
                                       (lds_void*)(lB + 8 * j * 64), 16, 0, 0);
    }
    __syncthreads();
#pragma unroll
    for (int kk = 0; kk < 2; ++kk) {
      int gq = ((kk << 2) + quad) ^ (lrow & 7);
      bf16x8 af[4], bfr[4];
#pragma unroll
      for (int i = 0; i < 4; ++i)
        af[i] = *(const bf16x8*)&As[(64 * wr + 16 * i + lrow) * 64 + gq * 8];
#pragma unroll
      for (int j = 0; j < 4; ++j)
        bfr[j] = *(const bf16x8*)&Bs[(64 * wc + 16 * j + lrow) * 64 + gq * 8];
#pragma unroll
      for (int i = 0; i < 4; ++i)
#pragma unroll
        for (int j = 0; j < 4; ++j)
          acc[i][j] = __builtin_amdgcn_mfma_f32_16x16x32_bf16(af[i], bfr[j], acc[i][j], 0, 0, 0);
    }
  }

  float bv[4];
#pragma unroll
  for (int j = 0; j < 4; ++j) bv[j] = bf2f(bi[n0 + 64 * wc + 16 * j + lrow]);
#pragma unroll
  for (int i = 0; i < 4; ++i) {
    int row = m0 + 64 * wr + 16 * i + 4 * quad;
#pragma unroll
    for (int j = 0; j < 4; ++j) {
      int col = n0 + 64 * wc + 16 * j + lrow;
#pragma unroll
      for (int r = 0; r < 4; ++r)
        C[(size_t)(row + r) * 1024 + col] = acc[i][j][r] + bv[j];
    }
  }
}

extern "C" void kernel_launch(void* const* d_in, const int* in_sizes, int n_in,
                              void* d_out, int out_size, void* d_ws, size_t ws_size,
                              hipStream_t stream) {
  (void)in_sizes; (void)n_in; (void)out_size; (void)ws_size;
  const size_t M1 = 1048576u;
  u16* ws = (u16*)d_ws;
  u16* wtA   = ws;             // [2048,1024] concat(Wa_qk^T*0.125*log2e, Wa_v^T)
  u16* wtB   = ws + 2 * M1;    // [2048,1024] concat(Wb_qk^T, Wb_v^T)
  u16* wtO   = ws + 4 * M1;    // [2048,1024] concat(Wa_o^T, Wb_o^T)
  u16* biasQ = ws + 6 * M1;    // [2,2048]
  u16* biasO = ws + 6 * M1 + 4096;  // [2,1024]
  u16* ab    = ws + 7 * M1;    // [2][4096,1024] bf16 inputs (dead after QKV)
  u16* vt    = ab;             // alias: [2][bh][64][2048]
  u16* qkbuf = ws + 15 * M1;   // [2][bh][2048][64]
  u16* vbuf  = ws + 23 * M1;   // [2][bh][2048][64] (dead after transpose_v)
  u16* ctx   = vbuf;           // alias: [2][4096,1024]

  dim3 blk(256);
  k_cvt_in<<<dim3(2048, 2), blk, 0, stream>>>((const float*)d_in[0],
                                              (const float*)d_in[1], ab);
  k_cvt_bias<<<dim3(4, 6), blk, 0, stream>>>(
      (const float*)d_in[3], (const float*)d_in[5], (const float*)d_in[7],
      (const float*)d_in[9], (const float*)d_in[11], (const float*)d_in[13], biasQ);
  k_transpose_w<<<dim3(16, 16, 6), blk, 0, stream>>>(
      (const float*)d_in[2], (const float*)d_in[4], (const float*)d_in[6],
      (const float*)d_in[8], (const float*)d_in[10], (const float*)d_in[12],
      wtA, wtA + M1, wtB, wtB + M1, wtO, wtO + M1);
  k_gemm_qkv<<<dim3(16, 32, 2), blk, 0, stream>>>(ab, wtA, wtB, biasQ, qkbuf, vbuf);
  k_transpose_v<<<dim3(32, 64), blk, 0, stream>>>(vbuf, vt);
  k_attn<<<dim3(32, 16, 2), blk, 0, stream>>>(qkbuf, vt, ctx);
  k_gemm_o<<<dim3(8, 32, 2), blk, 0, stream>>>(ctx, wtO, biasO, (float*)d_out);
}

// Round 9
// 276.130 us; speedup vs baseline: 1.1664x; 1.0693x over previous
//
#include <hip/hip_runtime.h>
#include <hip/hip_bf16.h>
#include <stdint.h>

typedef unsigned short u16;
typedef unsigned int u32;
typedef __attribute__((ext_vector_type(8))) short bf16x8;
typedef __attribute__((ext_vector_type(4))) float f32x4;

typedef __attribute__((address_space(3))) void lds_void;
typedef const __attribute__((address_space(1))) void gbl_void;

#define SIDE 4194304u   // 4M elems = one side's [B,H,2048,64] / [4096,1024]
#define BHSTR 131072u   // 2048*64 per (b,h)

static __device__ __forceinline__ u16 f2bf(float f) {
  union { __hip_bfloat16 b; u16 u; } cv;
  cv.b = __float2bfloat16(f);
  return cv.u;
}
static __device__ __forceinline__ float bf2f(u16 u) {
  union { __hip_bfloat16 b; u16 u; } cv;
  cv.u = u;
  return __bfloat162float(cv.b);
}

// raw v_exp_f32 (1 VALU op, 1 ULP): input already scaled by log2(e)
static __device__ __forceinline__ float fast_exp2(float x) {
#if __has_builtin(__builtin_amdgcn_exp2f)
  return __builtin_amdgcn_exp2f(x);
#else
  float r;
  asm("v_exp_f32 %0, %1" : "=v"(r) : "v"(x));
  return r;
#endif
}

// v_permlane16_swap_b32: row1(a)<->row0(b), row3(a)<->row2(b) (16-lane rows)
static __device__ __forceinline__ void pl16swap(u32& a, u32& b) {
#if __has_builtin(__builtin_amdgcn_permlane16_swap)
  typedef __attribute__((ext_vector_type(2))) unsigned int u32x2;
  u32x2 r = __builtin_amdgcn_permlane16_swap(a, b, 0, 0);
  a = r[0];
  b = r[1];
#else
  asm volatile("v_permlane16_swap_b32 %0, %1" : "+v"(a), "+v"(b));
#endif
}

// ---------------- input convert: a,b fp32 -> bf16 row-major ----------------
__global__ __launch_bounds__(256) void k_cvt_in(const float* __restrict__ a,
                                                const float* __restrict__ b,
                                                u16* __restrict__ dst) {
  int z = blockIdx.y;
  const float* src = z ? b : a;
  size_t i = ((size_t)blockIdx.x * 256 + threadIdx.x) * 8;
  float4 x0 = *(const float4*)(src + i);
  float4 x1 = *(const float4*)(src + i + 4);
  u16 t[8] = {f2bf(x0.x), f2bf(x0.y), f2bf(x0.z), f2bf(x0.w),
              f2bf(x1.x), f2bf(x1.y), f2bf(x1.z), f2bf(x1.w)};
  *(uint4*)(dst + (size_t)z * SIDE + i) = *(uint4*)t;
}

// ---------------- bias convert (fp32 -> bf16, concat, scale z0) -----------
// scale = 1/sqrt(D) * log2(e) so scores feed raw v_exp_f32 directly
__global__ __launch_bounds__(256) void k_cvt_bias(
    const float* s0, const float* s1, const float* s2, const float* s3,
    const float* s4, const float* s5, u16* __restrict__ dst) {
  const float* srcs[6] = {s0, s1, s2, s3, s4, s5};
  int z = blockIdx.y;
  int i = blockIdx.x * 256 + threadIdx.x;
  float sc = (z == 0) ? 0.18033688011112042f : 1.0f;  // 0.125 * log2(e)
  dst[z * 1024 + i] = f2bf(srcs[z][i] * sc);
}

// ---------------- weight transpose fp32 -> bf16, concat, scale z0 ---------
__global__ __launch_bounds__(256) void k_transpose_w(
    const float* a0, const float* a1, const float* a2, const float* a3,
    const float* a4, const float* a5,
    u16* d0, u16* d1, u16* d2, u16* d3, u16* d4, u16* d5) {
  __shared__ u16 tile[64][72];
  const float* srcs[6] = {a0, a1, a2, a3, a4, a5};
  u16* dsts[6] = {d0, d1, d2, d3, d4, d5};
  int z = blockIdx.z;
  float sc = (z == 0) ? 0.18033688011112042f : 1.0f;  // 0.125 * log2(e)
  const float* src = srcs[z] + (size_t)(blockIdx.y * 64) * 1024 + blockIdx.x * 64;
  int t = threadIdx.x;
  int row = t >> 2, c4 = t & 3;
#pragma unroll
  for (int p = 0; p < 2; ++p) {
    int col = c4 * 8 + p * 32;
    const float* sf = src + (size_t)row * 1024 + col;
    float4 x0 = *(const float4*)sf;
    float4 x1 = *(const float4*)(sf + 4);
    u16 tmp[8] = {f2bf(x0.x * sc), f2bf(x0.y * sc), f2bf(x0.z * sc), f2bf(x0.w * sc),
                  f2bf(x1.x * sc), f2bf(x1.y * sc), f2bf(x1.z * sc), f2bf(x1.w * sc)};
    *(uint4*)(&tile[row][col]) = *(uint4*)tmp;
  }
  __syncthreads();
  u16* dst = dsts[z] + (size_t)(blockIdx.x * 64) * 1024 + blockIdx.y * 64;
#pragma unroll
  for (int p = 0; p < 2; ++p) {
    int col = c4 * 8 + p * 32;
    u16 tmp[8];
#pragma unroll
    for (int i = 0; i < 8; ++i) tmp[i] = tile[col + i][row];
    *(uint4*)(dst + (size_t)row * 1024 + col) = *(uint4*)tmp;
  }
}

// ---------------- QKV projection: [4096,1024]bf16 @ WtAB[2048,1024]^T -----
// BK=64; [128][64] LDS tiles staged with XOR-granule swizzle.
__global__ __launch_bounds__(256) void k_gemm_qkv(
    const u16* __restrict__ Aall, const u16* __restrict__ WtA,
    const u16* __restrict__ WtB, const u16* __restrict__ bias,
    u16* __restrict__ qkbuf, u16* __restrict__ vbuf) {
  __shared__ u16 Sh[16384];   // As [128][64] + Bs [128][64] = 32KB
  u16* As = Sh;
  u16* Bs = Sh + 8192;
  int tid = threadIdx.x;
  int wave = tid >> 6, lane = tid & 63;
  int quad = lane >> 4, lrow = lane & 15;
  int wr = wave >> 1, wc = wave & 1;
  int z = blockIdx.z;
  int m0 = blockIdx.y * 128, n0 = blockIdx.x * 128;
  const u16* A = Aall + (size_t)z * SIDE;
  const u16* Wt = z ? WtB : WtA;
  const u16* bi = bias + (size_t)z * 2048;

  f32x4 acc[4][4] = {};
  int srow = 32 * wave + (lane >> 3);        // 8 lanes per 64-col row
  int ssw = ((lane & 7) ^ (lane >> 3)) * 8;  // inverse-swizzled source col
  const u16* gA = A + (size_t)(m0 + srow) * 1024 + ssw;
  const u16* gB = Wt + (size_t)(n0 + srow) * 1024 + ssw;
  u16* lA = &As[(32 * wave) * 64];
  u16* lB = &Bs[(32 * wave) * 64];

  for (int k0 = 0; k0 < 1024; k0 += 64) {
    __syncthreads();
#pragma unroll
    for (int j = 0; j < 4; ++j) {
      __builtin_amdgcn_global_load_lds((gbl_void*)(gA + (size_t)(8 * j) * 1024 + k0),
                                       (lds_void*)(lA + 8 * j * 64), 16, 0, 0);
      __builtin_amdgcn_global_load_lds((gbl_void*)(gB + (size_t)(8 * j) * 1024 + k0),
                                       (lds_void*)(lB + 8 * j * 64), 16, 0, 0);
    }
    __syncthreads();
#pragma unroll
    for (int kk = 0; kk < 2; ++kk) {
      int gq = ((kk << 2) + quad) ^ (lrow & 7);  // swizzled read granule
      bf16x8 af[4], bfr[4];
#pragma unroll
      for (int i = 0; i < 4; ++i)
        af[i] = *(const bf16x8*)&As[(64 * wr + 16 * i + lrow) * 64 + gq * 8];
#pragma unroll
      for (int j = 0; j < 4; ++j)
        bfr[j] = *(const bf16x8*)&Bs[(64 * wc + 16 * j + lrow) * 64 + gq * 8];
#pragma unroll
      for (int i = 0; i < 4; ++i)
#pragma unroll
        for (int j = 0; j < 4; ++j)
          acc[i][j] = __builtin_amdgcn_mfma_f32_16x16x32_bf16(af[i], bfr[j], acc[i][j], 0, 0, 0);
    }
  }

  float bv[4];
#pragma unroll
  for (int j = 0; j < 4; ++j) bv[j] = bf2f(bi[n0 + 64 * wc + 16 * j + lrow]);

  int x = blockIdx.x;
  bool isv = (x >= 8);
  int h = (isv ? 2 * (x - 8) : 2 * x) + wc;
  u16* dst = (isv ? vbuf : qkbuf) + (size_t)z * SIDE;
  u16* lw = Sh + wave * 1216;  // 16 rows * stride 76 per wave

  __syncthreads();  // all waves done reading As/Bs
#pragma unroll
  for (int i = 0; i < 4; ++i) {
#pragma unroll
    for (int j = 0; j < 4; ++j)
#pragma unroll
      for (int r = 0; r < 4; ++r)
        lw[(4 * quad + r) * 76 + 16 * j + lrow] = f2bf(acc[i][j][r] + bv[j]);
    asm volatile("s_waitcnt lgkmcnt(0)" ::: "memory");
    int row = lane >> 2, cg = (lane & 3) * 16;
    int rg = m0 + 64 * wr + 16 * i + row;
    int bb = rg >> 11, rl = rg & 2047;
    u16* dr = dst + (size_t)(bb * 16 + h) * BHSTR + (size_t)rl * 64 + cg;
    uint2 w0 = *(const uint2*)&lw[row * 76 + cg];
    uint2 w1 = *(const uint2*)&lw[row * 76 + cg + 4];
    uint2 w2 = *(const uint2*)&lw[row * 76 + cg + 8];
    uint2 w3 = *(const uint2*)&lw[row * 76 + cg + 12];
    uint4 o0 = {w0.x, w0.y, w1.x, w1.y};
    uint4 o1 = {w2.x, w2.y, w3.x, w3.y};
    *(uint4*)dr = o0;
    *(uint4*)(dr + 8) = o1;
    asm volatile("s_waitcnt lgkmcnt(0)" ::: "memory");  // WAR fence before next pass
  }
}

// ---------------- V transpose per head: [sbh][2048][64] -> [sbh][64][2048] --
__global__ __launch_bounds__(256) void k_transpose_v(const u16* __restrict__ v,
                                                     u16* __restrict__ vt) {
  __shared__ u16 tile[64][72];
  int sbh = blockIdx.y;
  int n0 = blockIdx.x * 64;
  const u16* src = v + (size_t)sbh * BHSTR + (size_t)n0 * 64;
  u16* dst = vt + (size_t)sbh * BHSTR + n0;
  int t = threadIdx.x;
  int row = t >> 2, c4 = t & 3;
#pragma unroll
  for (int p = 0; p < 2; ++p) {
    int col = c4 * 8 + p * 32;
    uint4 q = *(const uint4*)(src + (size_t)row * 64 + col);
    *(uint4*)(&tile[row][col]) = q;
  }
  __syncthreads();
#pragma unroll
  for (int p = 0; p < 2; ++p) {
    int col = c4 * 8 + p * 32;
    u16 tmp[8];
#pragma unroll
    for (int i = 0; i < 8; ++i) tmp[i] = tile[col + i][row];
    *(uint4*)(dst + (size_t)row * 2048 + col) = *(uint4*)tmp;
  }
}

// ---------------- fused dual-softmax attention, both sides ----------------
// z=0: Q=aq,K=bq,V=bv -> a_ctx ; z=1: Q=bq,K=aq,V=av -> b_ctx
// Round-3 hardware-verified permlane structure (KVBLK=64, K/V dbuf, P fully
// in registers via v_permlane16_swap with matched V-granule permutation,
// MFMA row-sums) + round-8 verified fast_exp2 (raw v_exp_f32, log2e
// pre-folded into Wa_qk/ba_qk).  Two independently-measured deltas composed.
__global__ __launch_bounds__(256, 4) void k_attn(
    const u16* __restrict__ qk, const u16* __restrict__ vt,
    u16* __restrict__ ctx) {
  __shared__ u16 Ks[2 * 4096];   // [2][64 s][64 d], granule-swizzled
  __shared__ u16 Vs[2 * 4096];   // [2][64 d][64 s], granule-swizzled
  int tid = threadIdx.x;
  int wave = tid >> 6, lane = tid & 63;
  int quad = lane >> 4, lrow = lane & 15;
  int z = blockIdx.z, bh = blockIdx.x;   // x=bh: l-tiles of one (z,bh) share an XCD
  int l0 = blockIdx.y * 128;
  const u16* Qb = qk + (size_t)z * SIDE + (size_t)bh * BHSTR + (size_t)l0 * 64;
  const u16* Kb = qk + (size_t)(1 - z) * SIDE + (size_t)bh * BHSTR;
  const u16* Vtb = vt + (size_t)(1 - z) * SIDE + (size_t)bh * BHSTR;

  // Q -> registers: wave owns rows 32*wave .. 32*wave+31
  bf16x8 qf[2][2];
#pragma unroll
  for (int rt = 0; rt < 2; ++rt) {
    int lq = 32 * wave + 16 * rt + lrow;
    qf[rt][0] = *(const bf16x8*)&Qb[(size_t)lq * 64 + 8 * quad];
    qf[rt][1] = *(const bf16x8*)&Qb[(size_t)lq * 64 + 32 + 8 * quad];
  }

  // staging lane constants: 512 granules per tile, 2 per thread (p=0,1)
  int r0 = tid >> 3, c0 = tid & 7;
  int r1 = (256 + tid) >> 3;             // c1 == c0
  const u16* kS0 = Kb + (size_t)r0 * 64 + ((c0 ^ (r0 & 7)) * 8);
  const u16* kS1 = Kb + (size_t)r1 * 64 + ((c0 ^ (r1 & 7)) * 8);
  const u16* vS0 = Vtb + (size_t)r0 * 2048 + ((c0 ^ (r0 & 7)) * 8);
  const u16* vS1 = Vtb + (size_t)r1 * 2048 + ((c0 ^ (r1 & 7)) * 8);
  u16* kD0 = Ks + (wave * 64) * 8;       // uniform base; HW adds lane*16B
  u16* kD1 = Ks + (256 + wave * 64) * 8;
  u16* vD0 = Vs + (wave * 64) * 8;
  u16* vD1 = Vs + (256 + wave * 64) * 8;

  bf16x8 ones;
  {
    short o = 0x3F80;  // bf16 1.0
#pragma unroll
    for (int i = 0; i < 8; ++i) ones[i] = o;
  }

  f32x4 cacc[2][4] = {};
  f32x4 asum[2] = {};
  int gsq = 2 * (quad & 1) + (quad >> 1);  // V granule permutation [0,2,1,3]

#define STAGE(BUFOFF, IT)                                                        \
  __builtin_amdgcn_global_load_lds((gbl_void*)(kS0 + (size_t)(IT)*4096),         \
                                   (lds_void*)(kD0 + (BUFOFF)), 16, 0, 0);       \
  __builtin_amdgcn_global_load_lds((gbl_void*)(kS1 + (size_t)(IT)*4096),         \
                                   (lds_void*)(kD1 + (BUFOFF)), 16, 0, 0);       \
  __builtin_amdgcn_global_load_lds((gbl_void*)(vS0 + (size_t)(IT)*64),           \
                                   (lds_void*)(vD0 + (BUFOFF)), 16, 0, 0);       \
  __builtin_amdgcn_global_load_lds((gbl_void*)(vS1 + (size_t)(IT)*64),           \
                                   (lds_void*)(vD1 + (BUFOFF)), 16, 0, 0);

#define ATT_BODY(BUFOFF)                                                         \
  {                                                                              \
    const u16* KsC = Ks + (BUFOFF);                                              \
    const u16* VsC = Vs + (BUFOFF);                                              \
    u32 X[2][4], Y[2][4];                                                        \
    _Pragma("unroll") for (int j = 0; j < 4; ++j) {                              \
      int kr = 16 * j + lrow;                                                    \
      bf16x8 kf0 = *(const bf16x8*)&KsC[(kr * 8 + (quad ^ (kr & 7))) * 8];       \
      bf16x8 kf1 = *(const bf16x8*)&KsC[(kr * 8 + ((quad + 4) ^ (kr & 7))) * 8]; \
      _Pragma("unroll") for (int rt = 0; rt < 2; ++rt) {                         \
        f32x4 s = {};                                                            \
        s = __builtin_amdgcn_mfma_f32_16x16x32_bf16(kf0, qf[rt][0], s, 0, 0, 0); \
        s = __builtin_amdgcn_mfma_f32_16x16x32_bf16(kf1, qf[rt][1], s, 0, 0, 0); \
        float e0 = fast_exp2(s[0]), e1 = fast_exp2(s[1]);                        \
        float e2 = fast_exp2(s[2]), e3 = fast_exp2(s[3]);                        \
        X[rt][j] = ((u32)f2bf(e1) << 16) | (u32)f2bf(e0);                        \
        Y[rt][j] = ((u32)f2bf(e3) << 16) | (u32)f2bf(e2);                        \
      }                                                                          \
    }                                                                            \
    bf16x8 pf[2][2];                                                             \
    _Pragma("unroll") for (int rt = 0; rt < 2; ++rt) {                           \
      pl16swap(X[rt][0], X[rt][1]);                                              \
      pl16swap(Y[rt][0], Y[rt][1]);                                              \
      pl16swap(X[rt][2], X[rt][3]);                                              \
      pl16swap(Y[rt][2], Y[rt][3]);                                              \
      union { u32 d[4]; bf16x8 v; } u0, u1;                                      \
      u0.d[0] = X[rt][0]; u0.d[1] = Y[rt][0];                                    \
      u0.d[2] = X[rt][1]; u0.d[3] = Y[rt][1];                                    \
      u1.d[0] = X[rt][2]; u1.d[1] = Y[rt][2];                                    \
      u1.d[2] = X[rt][3]; u1.d[3] = Y[rt][3];                                    \
      pf[rt][0] = u0.v;                                                          \
      pf[rt][1] = u1.v;                                                          \
    }                                                                            \
    _Pragma("unroll") for (int jd = 0; jd < 4; ++jd) {                           \
      int vr = 16 * jd + lrow;                                                   \
      bf16x8 vf0 = *(const bf16x8*)&VsC[(vr * 8 + (gsq ^ (vr & 7))) * 8];        \
      bf16x8 vf1 = *(const bf16x8*)&VsC[(vr * 8 + ((gsq | 4) ^ (vr & 7))) * 8];  \
      _Pragma("unroll") for (int rt = 0; rt < 2; ++rt) {                         \
        cacc[rt][jd] = __builtin_amdgcn_mfma_f32_16x16x32_bf16(pf[rt][0], vf0, cacc[rt][jd], 0, 0, 0); \
        cacc[rt][jd] = __builtin_amdgcn_mfma_f32_16x16x32_bf16(pf[rt][1], vf1, cacc[rt][jd], 0, 0, 0); \
      }                                                                          \
    }                                                                            \
    _Pragma("unroll") for (int rt = 0; rt < 2; ++rt) {                           \
      asum[rt] = __builtin_amdgcn_mfma_f32_16x16x32_bf16(pf[rt][0], ones, asum[rt], 0, 0, 0); \
      asum[rt] = __builtin_amdgcn_mfma_f32_16x16x32_bf16(pf[rt][1], ones, asum[rt], 0, 0, 0); \
    }                                                                            \
  }

  // prologue: stage round 0 into buffer 0
  STAGE(0, 0)

  for (int it2 = 0; it2 < 16; ++it2) {
    int it = 2 * it2;
    __syncthreads();          // buf0 staged (barrier drains vmcnt)
    STAGE(4096, it + 1)       // prefetch next round into buf1
    ATT_BODY(0)
    __syncthreads();          // buf1 staged
    if (it2 < 15) {
      STAGE(0, it + 2)        // prefetch round it+2 into buf0
    }
    ATT_BODY(4096)
  }
#undef ATT_BODY
#undef STAGE

  int bb = bh >> 4, h = bh & 15;
  u16* Ob = ctx + (size_t)z * SIDE + (size_t)(bb * 2048 + l0) * 1024 + h * 64;
#pragma unroll
  for (int rt = 0; rt < 2; ++rt) {
#pragma unroll
    for (int r = 0; r < 4; ++r) {
      float rinv = 1.0f / asum[rt][r];
      int l = 32 * wave + 16 * rt + 4 * quad + r;
#pragma unroll
      for (int j = 0; j < 4; ++j)
        Ob[(size_t)l * 1024 + 16 * j + lrow] = f2bf(cacc[rt][j][r] * rinv);
    }
  }
}

// ---------------- O projection: ctx[4096,1024]bf16 @ WtO^T + bias -> fp32 --
// BK=64, same swizzled staging as k_gemm_qkv.
__global__ __launch_bounds__(256) void k_gemm_o(
    const u16* __restrict__ ctx, const u16* __restrict__ WtO,
    const u16* __restrict__ bias, float* __restrict__ out) {
  __shared__ u16 As[128 * 64];
  __shared__ u16 Bs[128 * 64];
  int tid = threadIdx.x;
  int wave = tid >> 6, lane = tid & 63;
  int quad = lane >> 4, lrow = lane & 15;
  int wr = wave >> 1, wc = wave & 1;
  int z = blockIdx.z;
  int m0 = blockIdx.y * 128, n0 = blockIdx.x * 128;
  const u16* A = ctx + (size_t)z * SIDE;
  const u16* Wt = WtO + (size_t)z * 1048576;
  const u16* bi = bias + (size_t)z * 1024;
  float* C = out + (size_t)z * SIDE;

  f32x4 acc[4][4] = {};
  int srow = 32 * wave + (lane >> 3);
  int ssw = ((lane & 7) ^ (lane >> 3)) * 8;
  const u16* gA = A + (size_t)(m0 + srow) * 1024 + ssw;
  const u16* gB = Wt + (size_t)(n0 + srow) * 1024 + ssw;
  u16* lA = &As[(32 * wave) * 64];
  u16* lB = &Bs[(32 * wave) * 64];

  for (int k0 = 0; k0 < 1024; k0 += 64) {
    __syncthreads();
#pragma unroll
    for (int j = 0; j < 4; ++j) {
      __builtin_amdgcn_global_load_lds((gbl_void*)(gA + (size_t)(8 * j) * 1024 + k0),
                                       (lds_void*)(lA + 8 * j * 64), 16, 0, 0);
      __builtin_amdgcn_global_load_lds((gbl_void*)(gB + (size_t)(8 * j) * 1024 + k0),
                                       (lds_void*)(lB + 8 * j * 64), 16, 0, 0);
    }
    __syncthreads();
#pragma unroll
    for (int kk = 0; kk < 2; ++kk) {
      int gq = ((kk << 2) + quad) ^ (lrow & 7);
      bf16x8 af[4], bfr[4];
#pragma unroll
      for (int i = 0; i < 4; ++i)
        af[i] = *(const bf16x8*)&As[(64 * wr + 16 * i + lrow) * 64 + gq * 8];
#pragma unroll
      for (int j = 0; j < 4; ++j)
        bfr[j] = *(const bf16x8*)&Bs[(64 * wc + 16 * j + lrow) * 64 + gq * 8];
#pragma unroll
      for (int i = 0; i < 4; ++i)
#pragma unroll
        for (int j = 0; j < 4; ++j)
          acc[i][j] = __builtin_amdgcn_mfma_f32_16x16x32_bf16(af[i], bfr[j], acc[i][j], 0, 0, 0);
    }
  }

  float bv[4];
#pragma unroll
  for (int j = 0; j < 4; ++j) bv[j] = bf2f(bi[n0 + 64 * wc + 16 * j + lrow]);
#pragma unroll
  for (int i = 0; i < 4; ++i) {
    int row = m0 + 64 * wr + 16 * i + 4 * quad;
#pragma unroll
    for (int j = 0; j < 4; ++j) {
      int col = n0 + 64 * wc + 16 * j + lrow;
#pragma unroll
      for (int r = 0; r < 4; ++r)
        C[(size_t)(row + r) * 1024 + col] = acc[i][j][r] + bv[j];
    }
  }
}

extern "C" void kernel_launch(void* const* d_in, const int* in_sizes, int n_in,
                              void* d_out, int out_size, void* d_ws, size_t ws_size,
                              hipStream_t stream) {
  (void)in_sizes; (void)n_in; (void)out_size; (void)ws_size;
  const size_t M1 = 1048576u;
  u16* ws = (u16*)d_ws;
  u16* wtA   = ws;             // [2048,1024] concat(Wa_qk^T*0.125*log2e, Wa_v^T)
  u16* wtB   = ws + 2 * M1;    // [2048,1024] concat(Wb_qk^T, Wb_v^T)
  u16* wtO   = ws + 4 * M1;    // [2048,1024] concat(Wa_o^T, Wb_o^T)
  u16* biasQ = ws + 6 * M1;    // [2,2048]
  u16* biasO = ws + 6 * M1 + 4096;  // [2,1024]
  u16* ab    = ws + 7 * M1;    // [2][4096,1024] bf16 inputs (dead after QKV)
  u16* vt    = ab;             // alias: [2][bh][64][2048]
  u16* qkbuf = ws + 15 * M1;   // [2][bh][2048][64]
  u16* vbuf  = ws + 23 * M1;   // [2][bh][2048][64] (dead after transpose_v)
  u16* ctx   = vbuf;           // alias: [2][4096,1024]

  dim3 blk(256);
  k_cvt_in<<<dim3(2048, 2), blk, 0, stream>>>((const float*)d_in[0],
                                              (const float*)d_in[1], ab);
  k_cvt_bias<<<dim3(4, 6), blk, 0, stream>>>(
      (const float*)d_in[3], (const float*)d_in[5], (const float*)d_in[7],
      (const float*)d_in[9], (const float*)d_in[11], (const float*)d_in[13], biasQ);
  k_transpose_w<<<dim3(16, 16, 6), blk, 0, stream>>>(
      (const float*)d_in[2], (const float*)d_in[4], (const float*)d_in[6],
      (const float*)d_in[8], (const float*)d_in[10], (const float*)d_in[12],
      wtA, wtA + M1, wtB, wtB + M1, wtO, wtO + M1);
  k_gemm_qkv<<<dim3(16, 32, 2), blk, 0, stream>>>(ab, wtA, wtB, biasQ, qkbuf, vbuf);
  k_transpose_v<<<dim3(32, 64), blk, 0, stream>>>(vbuf, vt);
  k_attn<<<dim3(32, 16, 2), blk, 0, stream>>>(qkbuf, vt, ctx);
  k_gemm_o<<<dim3(8, 32, 2), blk, 0, stream>>>(ctx, wtO, biasO, (float*)d_out);
}

// Round 10
// 268.691 us; speedup vs baseline: 1.1987x; 1.0277x over previous
//
#include <hip/hip_runtime.h>
#include <hip/hip_bf16.h>
#include <stdint.h>

typedef unsigned short u16;
typedef unsigned int u32;
typedef __attribute__((ext_vector_type(8))) short bf16x8;
typedef __attribute__((ext_vector_type(4))) float f32x4;

typedef __attribute__((address_space(3))) void lds_void;
typedef const __attribute__((address_space(1))) void gbl_void;

#define SIDE 4194304u   // 4M elems = one side's [B,H,2048,64] / [4096,1024]
#define BHSTR 131072u   // 2048*64 per (b,h)

static __device__ __forceinline__ u16 f2bf(float f) {
  union { __hip_bfloat16 b; u16 u; } cv;
  cv.b = __float2bfloat16(f);
  return cv.u;
}
static __device__ __forceinline__ float bf2f(u16 u) {
  union { __hip_bfloat16 b; u16 u; } cv;
  cv.u = u;
  return __bfloat162float(cv.b);
}

// raw v_exp_f32 (1 VALU op, 1 ULP): input already scaled by log2(e)
static __device__ __forceinline__ float fast_exp2(float x) {
#if __has_builtin(__builtin_amdgcn_exp2f)
  return __builtin_amdgcn_exp2f(x);
#else
  float r;
  asm("v_exp_f32 %0, %1" : "=v"(r) : "v"(x));
  return r;
#endif
}

// v_permlane16_swap_b32: row1(a)<->row0(b), row3(a)<->row2(b) (16-lane rows)
static __device__ __forceinline__ void pl16swap(u32& a, u32& b) {
#if __has_builtin(__builtin_amdgcn_permlane16_swap)
  typedef __attribute__((ext_vector_type(2))) unsigned int u32x2;
  u32x2 r = __builtin_amdgcn_permlane16_swap(a, b, 0, 0);
  a = r[0];
  b = r[1];
#else
  asm volatile("v_permlane16_swap_b32 %0, %1" : "+v"(a), "+v"(b));
#endif
}

// ---------------- input convert: a,b fp32 -> bf16 row-major ----------------
__global__ __launch_bounds__(256) void k_cvt_in(const float* __restrict__ a,
                                                const float* __restrict__ b,
                                                u16* __restrict__ dst) {
  int z = blockIdx.y;
  const float* src = z ? b : a;
  size_t i = ((size_t)blockIdx.x * 256 + threadIdx.x) * 8;
  float4 x0 = *(const float4*)(src + i);
  float4 x1 = *(const float4*)(src + i + 4);
  u16 t[8] = {f2bf(x0.x), f2bf(x0.y), f2bf(x0.z), f2bf(x0.w),
              f2bf(x1.x), f2bf(x1.y), f2bf(x1.z), f2bf(x1.w)};
  *(uint4*)(dst + (size_t)z * SIDE + i) = *(uint4*)t;
}

// ---------------- bias convert (fp32 -> bf16, concat, scale z0) -----------
// scale = 1/sqrt(D) * log2(e) so scores feed raw v_exp_f32 directly
__global__ __launch_bounds__(256) void k_cvt_bias(
    const float* s0, const float* s1, const float* s2, const float* s3,
    const float* s4, const float* s5, u16* __restrict__ dst) {
  const float* srcs[6] = {s0, s1, s2, s3, s4, s5};
  int z = blockIdx.y;
  int i = blockIdx.x * 256 + threadIdx.x;
  float sc = (z == 0) ? 0.18033688011112042f : 1.0f;  // 0.125 * log2(e)
  dst[z * 1024 + i] = f2bf(srcs[z][i] * sc);
}

// ---------------- weight transpose fp32 -> bf16, concat, scale z0 ---------
__global__ __launch_bounds__(256) void k_transpose_w(
    const float* a0, const float* a1, const float* a2, const float* a3,
    const float* a4, const float* a5,
    u16* d0, u16* d1, u16* d2, u16* d3, u16* d4, u16* d5) {
  __shared__ u16 tile[64][72];
  const float* srcs[6] = {a0, a1, a2, a3, a4, a5};
  u16* dsts[6] = {d0, d1, d2, d3, d4, d5};
  int z = blockIdx.z;
  float sc = (z == 0) ? 0.18033688011112042f : 1.0f;  // 0.125 * log2(e)
  const float* src = srcs[z] + (size_t)(blockIdx.y * 64) * 1024 + blockIdx.x * 64;
  int t = threadIdx.x;
  int row = t >> 2, c4 = t & 3;
#pragma unroll
  for (int p = 0; p < 2; ++p) {
    int col = c4 * 8 + p * 32;
    const float* sf = src + (size_t)row * 1024 + col;
    float4 x0 = *(const float4*)sf;
    float4 x1 = *(const float4*)(sf + 4);
    u16 tmp[8] = {f2bf(x0.x * sc), f2bf(x0.y * sc), f2bf(x0.z * sc), f2bf(x0.w * sc),
                  f2bf(x1.x * sc), f2bf(x1.y * sc), f2bf(x1.z * sc), f2bf(x1.w * sc)};
    *(uint4*)(&tile[row][col]) = *(uint4*)tmp;
  }
  __syncthreads();
  u16* dst = dsts[z] + (size_t)(blockIdx.x * 64) * 1024 + blockIdx.y * 64;
#pragma unroll
  for (int p = 0; p < 2; ++p) {
    int col = c4 * 8 + p * 32;
    u16 tmp[8];
#pragma unroll
    for (int i = 0; i < 8; ++i) tmp[i] = tile[col + i][row];
    *(uint4*)(dst + (size_t)row * 1024 + col) = *(uint4*)tmp;
  }
}

// ---------------- QKV projection: [4096,1024]bf16 @ WtAB[2048,1024]^T -----
// BK=64, XOR-granule staging.  NEW: V heads are written TRANSPOSED
// ([bh][64][2048]) directly from the epilogue through the freed Sh LDS —
// k_transpose_v is deleted (saves a kernel + 34MB of vbuf round-trip).
__global__ __launch_bounds__(256) void k_gemm_qkv(
    const u16* __restrict__ Aall, const u16* __restrict__ WtA,
    const u16* __restrict__ WtB, const u16* __restrict__ bias,
    u16* __restrict__ qkbuf, u16* __restrict__ vtbuf) {
  __shared__ u16 Sh[16384];   // As [128][64] + Bs [128][64] = 32KB
  u16* As = Sh;
  u16* Bs = Sh + 8192;
  int tid = threadIdx.x;
  int wave = tid >> 6, lane = tid & 63;
  int quad = lane >> 4, lrow = lane & 15;
  int wr = wave >> 1, wc = wave & 1;
  int z = blockIdx.z;
  int m0 = blockIdx.y * 128, n0 = blockIdx.x * 128;
  const u16* A = Aall + (size_t)z * SIDE;
  const u16* Wt = z ? WtB : WtA;
  const u16* bi = bias + (size_t)z * 2048;

  f32x4 acc[4][4] = {};
  int srow = 32 * wave + (lane >> 3);        // 8 lanes per 64-col row
  int ssw = ((lane & 7) ^ (lane >> 3)) * 8;  // inverse-swizzled source col
  const u16* gA = A + (size_t)(m0 + srow) * 1024 + ssw;
  const u16* gB = Wt + (size_t)(n0 + srow) * 1024 + ssw;
  u16* lA = &As[(32 * wave) * 64];
  u16* lB = &Bs[(32 * wave) * 64];

  for (int k0 = 0; k0 < 1024; k0 += 64) {
    __syncthreads();
#pragma unroll
    for (int j = 0; j < 4; ++j) {
      __builtin_amdgcn_global_load_lds((gbl_void*)(gA + (size_t)(8 * j) * 1024 + k0),
                                       (lds_void*)(lA + 8 * j * 64), 16, 0, 0);
      __builtin_amdgcn_global_load_lds((gbl_void*)(gB + (size_t)(8 * j) * 1024 + k0),
                                       (lds_void*)(lB + 8 * j * 64), 16, 0, 0);
    }
    __syncthreads();
#pragma unroll
    for (int kk = 0; kk < 2; ++kk) {
      int gq = ((kk << 2) + quad) ^ (lrow & 7);  // swizzled read granule
      bf16x8 af[4], bfr[4];
#pragma unroll
      for (int i = 0; i < 4; ++i)
        af[i] = *(const bf16x8*)&As[(64 * wr + 16 * i + lrow) * 64 + gq * 8];
#pragma unroll
      for (int j = 0; j < 4; ++j)
        bfr[j] = *(const bf16x8*)&Bs[(64 * wc + 16 * j + lrow) * 64 + gq * 8];
#pragma unroll
      for (int i = 0; i < 4; ++i)
#pragma unroll
        for (int j = 0; j < 4; ++j)
          acc[i][j] = __builtin_amdgcn_mfma_f32_16x16x32_bf16(af[i], bfr[j], acc[i][j], 0, 0, 0);
    }
  }

  float bv[4];
#pragma unroll
  for (int j = 0; j < 4; ++j) bv[j] = bf2f(bi[n0 + 64 * wc + 16 * j + lrow]);

  int x = blockIdx.x;
  bool isv = (x >= 8);
  int h = (isv ? 2 * (x - 8) : 2 * x) + wc;

  __syncthreads();  // all waves done reading As/Bs; Sh free for epilogue

  if (isv) {
    // ---- V transposed epilogue: wave-private [64 d][64 l] tile, XOR'd ----
    u16* Vw = Sh + wave * 4096;
    int rg0 = m0 + 64 * wr;                // 64-aligned, no 2048-crossing
    int bb = rg0 >> 11, rl0 = rg0 & 2047;
#pragma unroll
    for (int i = 0; i < 4; ++i)
#pragma unroll
      for (int j = 0; j < 4; ++j) {
        int d = 16 * j + lrow;
        int gw = (2 * i + (quad >> 1)) ^ (d & 7);   // granule of l64=16i+4q+r
        u16 tmp[4];
#pragma unroll
        for (int r = 0; r < 4; ++r) tmp[r] = f2bf(acc[i][j][r] + bv[j]);
        *(uint2*)&Vw[d * 64 + (gw << 3) + 4 * (quad & 1)] = *(uint2*)tmp;
      }
    asm volatile("s_waitcnt lgkmcnt(0)" ::: "memory");  // wave-private tile
    u16* vdst = vtbuf + (size_t)z * SIDE + (size_t)(bb * 16 + h) * BHSTR + rl0;
#pragma unroll
    for (int p = 0; p < 8; ++p) {
      int d = 8 * p + (lane >> 3);
      int gr = (lane & 7) ^ (d & 7);
      uint4 q = *(const uint4*)&Vw[d * 64 + (gr << 3)];
      *(uint4*)(vdst + (size_t)d * 2048 + (lane & 7) * 8) = q;
    }
  } else {
    // ---- QK epilogue (unchanged): lw staging, [bh][2048][64] layout ----
    u16* dst = qkbuf + (size_t)z * SIDE;
    u16* lw = Sh + wave * 1216;  // 16 rows * stride 76 per wave
#pragma unroll
    for (int i = 0; i < 4; ++i) {
#pragma unroll
      for (int j = 0; j < 4; ++j)
#pragma unroll
        for (int r = 0; r < 4; ++r)
          lw[(4 * quad + r) * 76 + 16 * j + lrow] = f2bf(acc[i][j][r] + bv[j]);
      asm volatile("s_waitcnt lgkmcnt(0)" ::: "memory");
      int row = lane >> 2, cg = (lane & 3) * 16;
      int rg = m0 + 64 * wr + 16 * i + row;
      int bb = rg >> 11, rl = rg & 2047;
      u16* dr = dst + (size_t)(bb * 16 + h) * BHSTR + (size_t)rl * 64 + cg;
      uint2 w0 = *(const uint2*)&lw[row * 76 + cg];
      uint2 w1 = *(const uint2*)&lw[row * 76 + cg + 4];
      uint2 w2 = *(const uint2*)&lw[row * 76 + cg + 8];
      uint2 w3 = *(const uint2*)&lw[row * 76 + cg + 12];
      uint4 o0 = {w0.x, w0.y, w1.x, w1.y};
      uint4 o1 = {w2.x, w2.y, w3.x, w3.y};
      *(uint4*)dr = o0;
      *(uint4*)(dr + 8) = o1;
      asm volatile("s_waitcnt lgkmcnt(0)" ::: "memory");  // WAR fence before next pass
    }
  }
}

// ---------------- fused dual-softmax attention, both sides ----------------
// z=0: Q=aq,K=bq,V=bv -> a_ctx ; z=1: Q=bq,K=aq,V=av -> b_ctx
// Round-9 verified kernel, byte-identical: permlane structure + fast_exp2.
__global__ __launch_bounds__(256, 4) void k_attn(
    const u16* __restrict__ qk, const u16* __restrict__ vt,
    u16* __restrict__ ctx) {
  __shared__ u16 Ks[2 * 4096];   // [2][64 s][64 d], granule-swizzled
  __shared__ u16 Vs[2 * 4096];   // [2][64 d][64 s], granule-swizzled
  int tid = threadIdx.x;
  int wave = tid >> 6, lane = tid & 63;
  int quad = lane >> 4, lrow = lane & 15;
  int z = blockIdx.z, bh = blockIdx.x;   // x=bh: l-tiles of one (z,bh) share an XCD
  int l0 = blockIdx.y * 128;
  const u16* Qb = qk + (size_t)z * SIDE + (size_t)bh * BHSTR + (size_t)l0 * 64;
  const u16* Kb = qk + (size_t)(1 - z) * SIDE + (size_t)bh * BHSTR;
  const u16* Vtb = vt + (size_t)(1 - z) * SIDE + (size_t)bh * BHSTR;

  // Q -> registers: wave owns rows 32*wave .. 32*wave+31
  bf16x8 qf[2][2];
#pragma unroll
  for (int rt = 0; rt < 2; ++rt) {
    int lq = 32 * wave + 16 * rt + lrow;
    qf[rt][0] = *(const bf16x8*)&Qb[(size_t)lq * 64 + 8 * quad];
    qf[rt][1] = *(const bf16x8*)&Qb[(size_t)lq * 64 + 32 + 8 * quad];
  }

  // staging lane constants: 512 granules per tile, 2 per thread (p=0,1)
  int r0 = tid >> 3, c0 = tid & 7;
  int r1 = (256 + tid) >> 3;             // c1 == c0
  const u16* kS0 = Kb + (size_t)r0 * 64 + ((c0 ^ (r0 & 7)) * 8);
  const u16* kS1 = Kb + (size_t)r1 * 64 + ((c0 ^ (r1 & 7)) * 8);
  const u16* vS0 = Vtb + (size_t)r0 * 2048 + ((c0 ^ (r0 & 7)) * 8);
  const u16* vS1 = Vtb + (size_t)r1 * 2048 + ((c0 ^ (r1 & 7)) * 8);
  u16* kD0 = Ks + (wave * 64) * 8;       // uniform base; HW adds lane*16B
  u16* kD1 = Ks + (256 + wave * 64) * 8;
  u16* vD0 = Vs + (wave * 64) * 8;
  u16* vD1 = Vs + (256 + wave * 64) * 8;

  bf16x8 ones;
  {
    short o = 0x3F80;  // bf16 1.0
#pragma unroll
    for (int i = 0; i < 8; ++i) ones[i] = o;
  }

  f32x4 cacc[2][4] = {};
  f32x4 asum[2] = {};
  int gsq = 2 * (quad & 1) + (quad >> 1);  // V granule permutation [0,2,1,3]

#define STAGE(BUFOFF, IT)                                                        \
  __builtin_amdgcn_global_load_lds((gbl_void*)(kS0 + (size_t)(IT)*4096),         \
                                   (lds_void*)(kD0 + (BUFOFF)), 16, 0, 0);       \
  __builtin_amdgcn_global_load_lds((gbl_void*)(kS1 + (size_t)(IT)*4096),         \
                                   (lds_void*)(kD1 + (BUFOFF)), 16, 0, 0);       \
  __builtin_amdgcn_global_load_lds((gbl_void*)(vS0 + (size_t)(IT)*64),           \
                                   (lds_void*)(vD0 + (BUFOFF)), 16, 0, 0);       \
  __builtin_amdgcn_global_load_lds((gbl_void*)(vS1 + (size_t)(IT)*64),           \
                                   (lds_void*)(vD1 + (BUFOFF)), 16, 0, 0);

#define ATT_BODY(BUFOFF)                                                         \
  {                                                                              \
    const u16* KsC = Ks + (BUFOFF);                                              \
    const u16* VsC = Vs + (BUFOFF);                                              \
    u32 X[2][4], Y[2][4];                                                        \
    _Pragma("unroll") for (int j = 0; j < 4; ++j) {                              \
      int kr = 16 * j + lrow;                                                    \
      bf16x8 kf0 = *(const bf16x8*)&KsC[(kr * 8 + (quad ^ (kr & 7))) * 8];       \
      bf16x8 kf1 = *(const bf16x8*)&KsC[(kr * 8 + ((quad + 4) ^ (kr & 7))) * 8]; \
      _Pragma("unroll") for (int rt = 0; rt < 2; ++rt) {                         \
        f32x4 s = {};                                                            \
        s = __builtin_amdgcn_mfma_f32_16x16x32_bf16(kf0, qf[rt][0], s, 0, 0, 0); \
        s = __builtin_amdgcn_mfma_f32_16x16x32_bf16(kf1, qf[rt][1], s, 0, 0, 0); \
        float e0 = fast_exp2(s[0]), e1 = fast_exp2(s[1]);                        \
        float e2 = fast_exp2(s[2]), e3 = fast_exp2(s[3]);                        \
        X[rt][j] = ((u32)f2bf(e1) << 16) | (u32)f2bf(e0);                        \
        Y[rt][j] = ((u32)f2bf(e3) << 16) | (u32)f2bf(e2);                        \
      }                                                                          \
    }                                                                            \
    bf16x8 pf[2][2];                                                             \
    _Pragma("unroll") for (int rt = 0; rt < 2; ++rt) {                           \
      pl16swap(X[rt][0], X[rt][1]);                                              \
      pl16swap(Y[rt][0], Y[rt][1]);                                              \
      pl16swap(X[rt][2], X[rt][3]);                                              \
      pl16swap(Y[rt][2], Y[rt][3]);                                              \
      union { u32 d[4]; bf16x8 v; } u0, u1;                                      \
      u0.d[0] = X[rt][0]; u0.d[1] = Y[rt][0];                                    \
      u0.d[2] = X[rt][1]; u0.d[3] = Y[rt][1];                                    \
      u1.d[0] = X[rt][2]; u1.d[1] = Y[rt][2];                                    \
      u1.d[2] = X[rt][3]; u1.d[3] = Y[rt][3];                                    \
      pf[rt][0] = u0.v;                                                          \
      pf[rt][1] = u1.v;                                                          \
    }                                                                            \
    _Pragma("unroll") for (int jd = 0; jd < 4; ++jd) {                           \
      int vr = 16 * jd + lrow;                                                   \
      bf16x8 vf0 = *(const bf16x8*)&VsC[(vr * 8 + (gsq ^ (vr & 7))) * 8];        \
      bf16x8 vf1 = *(const bf16x8*)&VsC[(vr * 8 + ((gsq | 4) ^ (vr & 7))) * 8];  \
      _Pragma("unroll") for (int rt = 0; rt < 2; ++rt) {                         \
        cacc[rt][jd] = __builtin_amdgcn_mfma_f32_16x16x32_bf16(pf[rt][0], vf0, cacc[rt][jd], 0, 0, 0); \
        cacc[rt][jd] = __builtin_amdgcn_mfma_f32_16x16x32_bf16(pf[rt][1], vf1, cacc[rt][jd], 0, 0, 0); \
      }                                                                          \
    }                                                                            \
    _Pragma("unroll") for (int rt = 0; rt < 2; ++rt) {                           \
      asum[rt] = __builtin_amdgcn_mfma_f32_16x16x32_bf16(pf[rt][0], ones, asum[rt], 0, 0, 0); \
      asum[rt] = __builtin_amdgcn_mfma_f32_16x16x32_bf16(pf[rt][1], ones, asum[rt], 0, 0, 0); \
    }                                                                            \
  }

  // prologue: stage round 0 into buffer 0
  STAGE(0, 0)

  for (int it2 = 0; it2 < 16; ++it2) {
    int it = 2 * it2;
    __syncthreads();          // buf0 staged (barrier drains vmcnt)
    STAGE(4096, it + 1)       // prefetch next round into buf1
    ATT_BODY(0)
    __syncthreads();          // buf1 staged
    if (it2 < 15) {
      STAGE(0, it + 2)        // prefetch round it+2 into buf0
    }
    ATT_BODY(4096)
  }
#undef ATT_BODY
#undef STAGE

  int bb = bh >> 4, h = bh & 15;
  u16* Ob = ctx + (size_t)z * SIDE + (size_t)(bb * 2048 + l0) * 1024 + h * 64;
#pragma unroll
  for (int rt = 0; rt < 2; ++rt) {
#pragma unroll
    for (int r = 0; r < 4; ++r) {
      float rinv = 1.0f / asum[rt][r];
      int l = 32 * wave + 16 * rt + 4 * quad + r;
#pragma unroll
      for (int j = 0; j < 4; ++j)
        Ob[(size_t)l * 1024 + 16 * j + lrow] = f2bf(cacc[rt][j][r] * rinv);
    }
  }
}

// ---------------- O projection: ctx[4096,1024]bf16 @ WtO^T + bias -> fp32 --
// BK=64, same swizzled staging as k_gemm_qkv.
__global__ __launch_bounds__(256) void k_gemm_o(
    const u16* __restrict__ ctx, const u16* __restrict__ WtO,
    const u16* __restrict__ bias, float* __restrict__ out) {
  __shared__ u16 As[128 * 64];
  __shared__ u16 Bs[128 * 64];
  int tid = threadIdx.x;
  int wave = tid >> 6, lane = tid & 63;
  int quad = lane >> 4, lrow = lane & 15;
  int wr = wave >> 1, wc = wave & 1;
  int z = blockIdx.z;
  int m0 = blockIdx.y * 128, n0 = blockIdx.x * 128;
  const u16* A = ctx + (size_t)z * SIDE;
  const u16* Wt = WtO + (size_t)z * 1048576;
  const u16* bi = bias + (size_t)z * 1024;
  float* C = out + (size_t)z * SIDE;

  f32x4 acc[4][4] = {};
  int srow = 32 * wave + (lane >> 3);
  int ssw = ((lane & 7) ^ (lane >> 3)) * 8;
  const u16* gA = A + (size_t)(m0 + srow) * 1024 + ssw;
  const u16* gB = Wt + (size_t)(n0 + srow) * 1024 + ssw;
  u16* lA = &As[(32 * wave) * 64];
  u16* lB = &Bs[(32 * wave) * 64];

  for (int k0 = 0; k0 < 1024; k0 += 64) {
    __syncthreads();
#pragma unroll
    for (int j = 0; j < 4; ++j) {
      __builtin_amdgcn_global_load_lds((gbl_void*)(gA + (size_t)(8 * j) * 1024 + k0),
                                       (lds_void*)(lA + 8 * j * 64), 16, 0, 0);
      __builtin_amdgcn_global_load_lds((gbl_void*)(gB + (size_t)(8 * j) * 1024 + k0),
                                       (lds_void*)(lB + 8 * j * 64), 16, 0, 0);
    }
    __syncthreads();
#pragma unroll
    for (int kk = 0; kk < 2; ++kk) {
      int gq = ((kk << 2) + quad) ^ (lrow & 7);
      bf16x8 af[4], bfr[4];
#pragma unroll
      for (int i = 0; i < 4; ++i)
        af[i] = *(const bf16x8*)&As[(64 * wr + 16 * i + lrow) * 64 + gq * 8];
#pragma unroll
      for (int j = 0; j < 4; ++j)
        bfr[j] = *(const bf16x8*)&Bs[(64 * wc + 16 * j + lrow) * 64 + gq * 8];
#pragma unroll
      for (int i = 0; i < 4; ++i)
#pragma unroll
        for (int j = 0; j < 4; ++j)
          acc[i][j] = __builtin_amdgcn_mfma_f32_16x16x32_bf16(af[i], bfr[j], acc[i][j], 0, 0, 0);
    }
  }

  float bv[4];
#pragma unroll
  for (int j = 0; j < 4; ++j) bv[j] = bf2f(bi[n0 + 64 * wc + 16 * j + lrow]);
#pragma unroll
  for (int i = 0; i < 4; ++i) {
    int row = m0 + 64 * wr + 16 * i + 4 * quad;
#pragma unroll
    for (int j = 0; j < 4; ++j) {
      int col = n0 + 64 * wc + 16 * j + lrow;
#pragma unroll
      for (int r = 0; r < 4; ++r)
        C[(size_t)(row + r) * 1024 + col] = acc[i][j][r] + bv[j];
    }
  }
}

extern "C" void kernel_launch(void* const* d_in, const int* in_sizes, int n_in,
                              void* d_out, int out_size, void* d_ws, size_t ws_size,
                              hipStream_t stream) {
  (void)in_sizes; (void)n_in; (void)out_size; (void)ws_size;
  const size_t M1 = 1048576u;
  u16* ws = (u16*)d_ws;
  u16* wtA   = ws;             // [2048,1024] concat(Wa_qk^T*0.125*log2e, Wa_v^T)
  u16* wtB   = ws + 2 * M1;    // [2048,1024] concat(Wb_qk^T, Wb_v^T)
  u16* wtO   = ws + 4 * M1;    // [2048,1024] concat(Wa_o^T, Wb_o^T)
  u16* biasQ = ws + 6 * M1;    // [2,2048]
  u16* biasO = ws + 6 * M1 + 4096;  // [2,1024]
  u16* ab    = ws + 7 * M1;    // [2][4096,1024] bf16 inputs (dead after QKV)
  u16* ctx   = ab;             // alias: [2][4096,1024] (attn output)
  u16* qkbuf = ws + 15 * M1;   // [2][bh][2048][64]
  u16* vt    = ws + 23 * M1;   // [2][bh][64][2048] (written by gemm_qkv)

  dim3 blk(256);
  k_cvt_in<<<dim3(2048, 2), blk, 0, stream>>>((const float*)d_in[0],
                                              (const float*)d_in[1], ab);
  k_cvt_bias<<<dim3(4, 6), blk, 0, stream>>>(
      (const float*)d_in[3], (const float*)d_in[5], (const float*)d_in[7],
      (const float*)d_in[9], (const float*)d_in[11], (const float*)d_in[13], biasQ);
  k_transpose_w<<<dim3(16, 16, 6), blk, 0, stream>>>(
      (const float*)d_in[2], (const float*)d_in[4], (const float*)d_in[6],
      (const float*)d_in[8], (const float*)d_in[10], (const float*)d_in[12],
      wtA, wtA + M1, wtB, wtB + M1, wtO, wtO + M1);
  k_gemm_qkv<<<dim3(16, 32, 2), blk, 0, stream>>>(ab, wtA, wtB, biasQ, qkbuf, vt);
  k_attn<<<dim3(32, 16, 2), blk, 0, stream>>>(qkbuf, vt, ctx);
  k_gemm_o<<<dim3(8, 32, 2), blk, 0, stream>>>(ctx, wtO, biasO, (float*)d_out);
}

// Round 11
// 262.242 us; speedup vs baseline: 1.2282x; 1.0246x over previous
//
#include <hip/hip_runtime.h>
#include <hip/hip_bf16.h>
#include <stdint.h>

typedef unsigned short u16;
typedef unsigned int u32;
typedef __attribute__((ext_vector_type(8))) short bf16x8;
typedef __attribute__((ext_vector_type(4))) float f32x4;

typedef __attribute__((address_space(3))) void lds_void;
typedef const __attribute__((address_space(1))) void gbl_void;

#define SIDE 4194304u   // 4M elems = one side's [B,H,2048,64] / [4096,1024]
#define BHSTR 131072u   // 2048*64 per (b,h)

static __device__ __forceinline__ u16 f2bf(float f) {
  union { __hip_bfloat16 b; u16 u; } cv;
  cv.b = __float2bfloat16(f);
  return cv.u;
}
static __device__ __forceinline__ float bf2f(u16 u) {
  union { __hip_bfloat16 b; u16 u; } cv;
  cv.u = u;
  return __bfloat162float(cv.b);
}

// raw v_exp_f32 (1 VALU op, 1 ULP): input already scaled by log2(e)
static __device__ __forceinline__ float fast_exp2(float x) {
#if __has_builtin(__builtin_amdgcn_exp2f)
  return __builtin_amdgcn_exp2f(x);
#else
  float r;
  asm("v_exp_f32 %0, %1" : "=v"(r) : "v"(x));
  return r;
#endif
}

// v_permlane16_swap_b32: row1(a)<->row0(b), row3(a)<->row2(b) (16-lane rows)
static __device__ __forceinline__ void pl16swap(u32& a, u32& b) {
#if __has_builtin(__builtin_amdgcn_permlane16_swap)
  typedef __attribute__((ext_vector_type(2))) unsigned int u32x2;
  u32x2 r = __builtin_amdgcn_permlane16_swap(a, b, 0, 0);
  a = r[0];
  b = r[1];
#else
  asm volatile("v_permlane16_swap_b32 %0, %1" : "+v"(a), "+v"(b));
#endif
}

// ---------------- input convert: a,b fp32 -> bf16 row-major ----------------
__global__ __launch_bounds__(256) void k_cvt_in(const float* __restrict__ a,
                                                const float* __restrict__ b,
                                                u16* __restrict__ dst) {
  int z = blockIdx.y;
  const float* src = z ? b : a;
  size_t i = ((size_t)blockIdx.x * 256 + threadIdx.x) * 8;
  float4 x0 = *(const float4*)(src + i);
  float4 x1 = *(const float4*)(src + i + 4);
  u16 t[8] = {f2bf(x0.x), f2bf(x0.y), f2bf(x0.z), f2bf(x0.w),
              f2bf(x1.x), f2bf(x1.y), f2bf(x1.z), f2bf(x1.w)};
  *(uint4*)(dst + (size_t)z * SIDE + i) = *(uint4*)t;
}

// ---------------- bias convert (fp32 -> bf16, concat, scale z0) -----------
// scale = 1/sqrt(D) * log2(e) so scores feed raw v_exp_f32 directly
__global__ __launch_bounds__(256) void k_cvt_bias(
    const float* s0, const float* s1, const float* s2, const float* s3,
    const float* s4, const float* s5, u16* __restrict__ dst) {
  const float* srcs[6] = {s0, s1, s2, s3, s4, s5};
  int z = blockIdx.y;
  int i = blockIdx.x * 256 + threadIdx.x;
  float sc = (z == 0) ? 0.18033688011112042f : 1.0f;  // 0.125 * log2(e)
  dst[z * 1024 + i] = f2bf(srcs[z][i] * sc);
}

// ---------------- weight transpose fp32 -> bf16, concat, scale z0 ---------
__global__ __launch_bounds__(256) void k_transpose_w(
    const float* a0, const float* a1, const float* a2, const float* a3,
    const float* a4, const float* a5,
    u16* d0, u16* d1, u16* d2, u16* d3, u16* d4, u16* d5) {
  __shared__ u16 tile[64][72];
  const float* srcs[6] = {a0, a1, a2, a3, a4, a5};
  u16* dsts[6] = {d0, d1, d2, d3, d4, d5};
  int z = blockIdx.z;
  float sc = (z == 0) ? 0.18033688011112042f : 1.0f;  // 0.125 * log2(e)
  const float* src = srcs[z] + (size_t)(blockIdx.y * 64) * 1024 + blockIdx.x * 64;
  int t = threadIdx.x;
  int row = t >> 2, c4 = t & 3;
#pragma unroll
  for (int p = 0; p < 2; ++p) {
    int col = c4 * 8 + p * 32;
    const float* sf = src + (size_t)row * 1024 + col;
    float4 x0 = *(const float4*)sf;
    float4 x1 = *(const float4*)(sf + 4);
    u16 tmp[8] = {f2bf(x0.x * sc), f2bf(x0.y * sc), f2bf(x0.z * sc), f2bf(x0.w * sc),
                  f2bf(x1.x * sc), f2bf(x1.y * sc), f2bf(x1.z * sc), f2bf(x1.w * sc)};
    *(uint4*)(&tile[row][col]) = *(uint4*)tmp;
  }
  __syncthreads();
  u16* dst = dsts[z] + (size_t)(blockIdx.x * 64) * 1024 + blockIdx.y * 64;
#pragma unroll
  for (int p = 0; p < 2; ++p) {
    int col = c4 * 8 + p * 32;
    u16 tmp[8];
#pragma unroll
    for (int i = 0; i < 8; ++i) tmp[i] = tile[col + i][row];
    *(uint4*)(dst + (size_t)row * 1024 + col) = *(uint4*)tmp;
  }
}

// ---------------- QKV projection: [4096,1024]bf16 @ WtAB[2048,1024]^T -----
// BK=64, XOR-granule staging, fused transposed-V epilogue.
// NEW: XCD-chunked block swizzle (nwg=1024, 8|1024 -> bijective): each XCD
// gets 8 contiguous m-panels instead of round-robin re-fetching every panel.
__global__ __launch_bounds__(256) void k_gemm_qkv(
    const u16* __restrict__ Aall, const u16* __restrict__ WtA,
    const u16* __restrict__ WtB, const u16* __restrict__ bias,
    u16* __restrict__ qkbuf, u16* __restrict__ vtbuf) {
  __shared__ u16 Sh[16384];   // As [128][64] + Bs [128][64] = 32KB
  u16* As = Sh;
  u16* Bs = Sh + 8192;
  int tid = threadIdx.x;
  int wave = tid >> 6, lane = tid & 63;
  int quad = lane >> 4, lrow = lane & 15;
  int wr = wave >> 1, wc = wave & 1;
  // XCD-chunked swizzle: hw id -> work id (grid 16x32x2 = 1024, cpx=128)
  int lin = blockIdx.x + 16 * blockIdx.y + 512 * blockIdx.z;
  int s = (lin & 7) * 128 + (lin >> 3);
  int bx = s & 15, by = (s >> 4) & 31, bz = s >> 9;
  int z = bz;
  int m0 = by * 128, n0 = bx * 128;
  const u16* A = Aall + (size_t)z * SIDE;
  const u16* Wt = z ? WtB : WtA;
  const u16* bi = bias + (size_t)z * 2048;

  f32x4 acc[4][4] = {};
  int srow = 32 * wave + (lane >> 3);        // 8 lanes per 64-col row
  int ssw = ((lane & 7) ^ (lane >> 3)) * 8;  // inverse-swizzled source col
  const u16* gA = A + (size_t)(m0 + srow) * 1024 + ssw;
  const u16* gB = Wt + (size_t)(n0 + srow) * 1024 + ssw;
  u16* lA = &As[(32 * wave) * 64];
  u16* lB = &Bs[(32 * wave) * 64];

  for (int k0 = 0; k0 < 1024; k0 += 64) {
    __syncthreads();
#pragma unroll
    for (int j = 0; j < 4; ++j) {
      __builtin_amdgcn_global_load_lds((gbl_void*)(gA + (size_t)(8 * j) * 1024 + k0),
                                       (lds_void*)(lA + 8 * j * 64), 16, 0, 0);
      __builtin_amdgcn_global_load_lds((gbl_void*)(gB + (size_t)(8 * j) * 1024 + k0),
                                       (lds_void*)(lB + 8 * j * 64), 16, 0, 0);
    }
    __syncthreads();
#pragma unroll
    for (int kk = 0; kk < 2; ++kk) {
      int gq = ((kk << 2) + quad) ^ (lrow & 7);  // swizzled read granule
      bf16x8 af[4], bfr[4];
#pragma unroll
      for (int i = 0; i < 4; ++i)
        af[i] = *(const bf16x8*)&As[(64 * wr + 16 * i + lrow) * 64 + gq * 8];
#pragma unroll
      for (int j = 0; j < 4; ++j)
        bfr[j] = *(const bf16x8*)&Bs[(64 * wc + 16 * j + lrow) * 64 + gq * 8];
#pragma unroll
      for (int i = 0; i < 4; ++i)
#pragma unroll
        for (int j = 0; j < 4; ++j)
          acc[i][j] = __builtin_amdgcn_mfma_f32_16x16x32_bf16(af[i], bfr[j], acc[i][j], 0, 0, 0);
    }
  }

  float bv[4];
#pragma unroll
  for (int j = 0; j < 4; ++j) bv[j] = bf2f(bi[n0 + 64 * wc + 16 * j + lrow]);

  bool isv = (bx >= 8);
  int h = (isv ? 2 * (bx - 8) : 2 * bx) + wc;

  __syncthreads();  // all waves done reading As/Bs; Sh free for epilogue

  if (isv) {
    // ---- V transposed epilogue: wave-private [64 d][64 l] tile, XOR'd ----
    u16* Vw = Sh + wave * 4096;
    int rg0 = m0 + 64 * wr;                // 64-aligned, no 2048-crossing
    int bb = rg0 >> 11, rl0 = rg0 & 2047;
#pragma unroll
    for (int i = 0; i < 4; ++i)
#pragma unroll
      for (int j = 0; j < 4; ++j) {
        int d = 16 * j + lrow;
        int gw = (2 * i + (quad >> 1)) ^ (d & 7);   // granule of l64=16i+4q+r
        u16 tmp[4];
#pragma unroll
        for (int r = 0; r < 4; ++r) tmp[r] = f2bf(acc[i][j][r] + bv[j]);
        *(uint2*)&Vw[d * 64 + (gw << 3) + 4 * (quad & 1)] = *(uint2*)tmp;
      }
    asm volatile("s_waitcnt lgkmcnt(0)" ::: "memory");  // wave-private tile
    u16* vdst = vtbuf + (size_t)z * SIDE + (size_t)(bb * 16 + h) * BHSTR + rl0;
#pragma unroll
    for (int p = 0; p < 8; ++p) {
      int d = 8 * p + (lane >> 3);
      int gr = (lane & 7) ^ (d & 7);
      uint4 q = *(const uint4*)&Vw[d * 64 + (gr << 3)];
      *(uint4*)(vdst + (size_t)d * 2048 + (lane & 7) * 8) = q;
    }
  } else {
    // ---- QK epilogue (unchanged): lw staging, [bh][2048][64] layout ----
    u16* dst = qkbuf + (size_t)z * SIDE;
    u16* lw = Sh + wave * 1216;  // 16 rows * stride 76 per wave
#pragma unroll
    for (int i = 0; i < 4; ++i) {
#pragma unroll
      for (int j = 0; j < 4; ++j)
#pragma unroll
        for (int r = 0; r < 4; ++r)
          lw[(4 * quad + r) * 76 + 16 * j + lrow] = f2bf(acc[i][j][r] + bv[j]);
      asm volatile("s_waitcnt lgkmcnt(0)" ::: "memory");
      int row = lane >> 2, cg = (lane & 3) * 16;
      int rg = m0 + 64 * wr + 16 * i + row;
      int bb = rg >> 11, rl = rg & 2047;
      u16* dr = dst + (size_t)(bb * 16 + h) * BHSTR + (size_t)rl * 64 + cg;
      uint2 w0 = *(const uint2*)&lw[row * 76 + cg];
      uint2 w1 = *(const uint2*)&lw[row * 76 + cg + 4];
      uint2 w2 = *(const uint2*)&lw[row * 76 + cg + 8];
      uint2 w3 = *(const uint2*)&lw[row * 76 + cg + 12];
      uint4 o0 = {w0.x, w0.y, w1.x, w1.y};
      uint4 o1 = {w2.x, w2.y, w3.x, w3.y};
      *(uint4*)dr = o0;
      *(uint4*)(dr + 8) = o1;
      asm volatile("s_waitcnt lgkmcnt(0)" ::: "memory");  // WAR fence before next pass
    }
  }
}

// ---------------- fused dual-softmax attention, both sides ----------------
// z=0: Q=aq,K=bq,V=bv -> a_ctx ; z=1: Q=bq,K=aq,V=av -> b_ctx
// Round-9 verified kernel + T5: s_setprio(1) around the PV+rowsum MFMA
// cluster (attn-positive per m191; waves diverge in phase between barriers).
__global__ __launch_bounds__(256, 4) void k_attn(
    const u16* __restrict__ qk, const u16* __restrict__ vt,
    u16* __restrict__ ctx) {
  __shared__ u16 Ks[2 * 4096];   // [2][64 s][64 d], granule-swizzled
  __shared__ u16 Vs[2 * 4096];   // [2][64 d][64 s], granule-swizzled
  int tid = threadIdx.x;
  int wave = tid >> 6, lane = tid & 63;
  int quad = lane >> 4, lrow = lane & 15;
  int z = blockIdx.z, bh = blockIdx.x;   // x=bh: l-tiles of one (z,bh) share an XCD
  int l0 = blockIdx.y * 128;
  const u16* Qb = qk + (size_t)z * SIDE + (size_t)bh * BHSTR + (size_t)l0 * 64;
  const u16* Kb = qk + (size_t)(1 - z) * SIDE + (size_t)bh * BHSTR;
  const u16* Vtb = vt + (size_t)(1 - z) * SIDE + (size_t)bh * BHSTR;

  // Q -> registers: wave owns rows 32*wave .. 32*wave+31
  bf16x8 qf[2][2];
#pragma unroll
  for (int rt = 0; rt < 2; ++rt) {
    int lq = 32 * wave + 16 * rt + lrow;
    qf[rt][0] = *(const bf16x8*)&Qb[(size_t)lq * 64 + 8 * quad];
    qf[rt][1] = *(const bf16x8*)&Qb[(size_t)lq * 64 + 32 + 8 * quad];
  }

  // staging lane constants: 512 granules per tile, 2 per thread (p=0,1)
  int r0 = tid >> 3, c0 = tid & 7;
  int r1 = (256 + tid) >> 3;             // c1 == c0
  const u16* kS0 = Kb + (size_t)r0 * 64 + ((c0 ^ (r0 & 7)) * 8);
  const u16* kS1 = Kb + (size_t)r1 * 64 + ((c0 ^ (r1 & 7)) * 8);
  const u16* vS0 = Vtb + (size_t)r0 * 2048 + ((c0 ^ (r0 & 7)) * 8);
  const u16* vS1 = Vtb + (size_t)r1 * 2048 + ((c0 ^ (r1 & 7)) * 8);
  u16* kD0 = Ks + (wave * 64) * 8;       // uniform base; HW adds lane*16B
  u16* kD1 = Ks + (256 + wave * 64) * 8;
  u16* vD0 = Vs + (wave * 64) * 8;
  u16* vD1 = Vs + (256 + wave * 64) * 8;

  bf16x8 ones;
  {
    short o = 0x3F80;  // bf16 1.0
#pragma unroll
    for (int i = 0; i < 8; ++i) ones[i] = o;
  }

  f32x4 cacc[2][4] = {};
  f32x4 asum[2] = {};
  int gsq = 2 * (quad & 1) + (quad >> 1);  // V granule permutation [0,2,1,3]

#define STAGE(BUFOFF, IT)                                                        \
  __builtin_amdgcn_global_load_lds((gbl_void*)(kS0 + (size_t)(IT)*4096),         \
                                   (lds_void*)(kD0 + (BUFOFF)), 16, 0, 0);       \
  __builtin_amdgcn_global_load_lds((gbl_void*)(kS1 + (size_t)(IT)*4096),         \
                                   (lds_void*)(kD1 + (BUFOFF)), 16, 0, 0);       \
  __builtin_amdgcn_global_load_lds((gbl_void*)(vS0 + (size_t)(IT)*64),           \
                                   (lds_void*)(vD0 + (BUFOFF)), 16, 0, 0);       \
  __builtin_amdgcn_global_load_lds((gbl_void*)(vS1 + (size_t)(IT)*64),           \
                                   (lds_void*)(vD1 + (BUFOFF)), 16, 0, 0);

#define ATT_BODY(BUFOFF)                                                         \
  {                                                                              \
    const u16* KsC = Ks + (BUFOFF);                                              \
    const u16* VsC = Vs + (BUFOFF);                                              \
    u32 X[2][4], Y[2][4];                                                        \
    _Pragma("unroll") for (int j = 0; j < 4; ++j) {                              \
      int kr = 16 * j + lrow;                                                    \
      bf16x8 kf0 = *(const bf16x8*)&KsC[(kr * 8 + (quad ^ (kr & 7))) * 8];       \
      bf16x8 kf1 = *(const bf16x8*)&KsC[(kr * 8 + ((quad + 4) ^ (kr & 7))) * 8]; \
      _Pragma("unroll") for (int rt = 0; rt < 2; ++rt) {                         \
        f32x4 s = {};                                                            \
        s = __builtin_amdgcn_mfma_f32_16x16x32_bf16(kf0, qf[rt][0], s, 0, 0, 0); \
        s = __builtin_amdgcn_mfma_f32_16x16x32_bf16(kf1, qf[rt][1], s, 0, 0, 0); \
        float e0 = fast_exp2(s[0]), e1 = fast_exp2(s[1]);                        \
        float e2 = fast_exp2(s[2]), e3 = fast_exp2(s[3]);                        \
        X[rt][j] = ((u32)f2bf(e1) << 16) | (u32)f2bf(e0);                        \
        Y[rt][j] = ((u32)f2bf(e3) << 16) | (u32)f2bf(e2);                        \
      }                                                                          \
    }                                                                            \
    bf16x8 pf[2][2];                                                             \
    _Pragma("unroll") for (int rt = 0; rt < 2; ++rt) {                           \
      pl16swap(X[rt][0], X[rt][1]);                                              \
      pl16swap(Y[rt][0], Y[rt][1]);                                              \
      pl16swap(X[rt][2], X[rt][3]);                                              \
      pl16swap(Y[rt][2], Y[rt][3]);                                              \
      union { u32 d[4]; bf16x8 v; } u0, u1;                                      \
      u0.d[0] = X[rt][0]; u0.d[1] = Y[rt][0];                                    \
      u0.d[2] = X[rt][1]; u0.d[3] = Y[rt][1];                                    \
      u1.d[0] = X[rt][2]; u1.d[1] = Y[rt][2];                                    \
      u1.d[2] = X[rt][3]; u1.d[3] = Y[rt][3];                                    \
      pf[rt][0] = u0.v;                                                          \
      pf[rt][1] = u1.v;                                                          \
    }                                                                            \
    __builtin_amdgcn_s_setprio(1);                                               \
    _Pragma("unroll") for (int jd = 0; jd < 4; ++jd) {                           \
      int vr = 16 * jd + lrow;                                                   \
      bf16x8 vf0 = *(const bf16x8*)&VsC[(vr * 8 + (gsq ^ (vr & 7))) * 8];        \
      bf16x8 vf1 = *(const bf16x8*)&VsC[(vr * 8 + ((gsq | 4) ^ (vr & 7))) * 8];  \
      _Pragma("unroll") for (int rt = 0; rt < 2; ++rt) {                         \
        cacc[rt][jd] = __builtin_amdgcn_mfma_f32_16x16x32_bf16(pf[rt][0], vf0, cacc[rt][jd], 0, 0, 0); \
        cacc[rt][jd] = __builtin_amdgcn_mfma_f32_16x16x32_bf16(pf[rt][1], vf1, cacc[rt][jd], 0, 0, 0); \
      }                                                                          \
    }                                                                            \
    _Pragma("unroll") for (int rt = 0; rt < 2; ++rt) {                           \
      asum[rt] = __builtin_amdgcn_mfma_f32_16x16x32_bf16(pf[rt][0], ones, asum[rt], 0, 0, 0); \
      asum[rt] = __builtin_amdgcn_mfma_f32_16x16x32_bf16(pf[rt][1], ones, asum[rt], 0, 0, 0); \
    }                                                                            \
    __builtin_amdgcn_s_setprio(0);                                               \
  }

  // prologue: stage round 0 into buffer 0
  STAGE(0, 0)

  for (int it2 = 0; it2 < 16; ++it2) {
    int it = 2 * it2;
    __syncthreads();          // buf0 staged (barrier drains vmcnt)
    STAGE(4096, it + 1)       // prefetch next round into buf1
    ATT_BODY(0)
    __syncthreads();          // buf1 staged
    if (it2 < 15) {
      STAGE(0, it + 2)        // prefetch round it+2 into buf0
    }
    ATT_BODY(4096)
  }
#undef ATT_BODY
#undef STAGE

  int bb = bh >> 4, h = bh & 15;
  u16* Ob = ctx + (size_t)z * SIDE + (size_t)(bb * 2048 + l0) * 1024 + h * 64;
#pragma unroll
  for (int rt = 0; rt < 2; ++rt) {
#pragma unroll
    for (int r = 0; r < 4; ++r) {
      float rinv = 1.0f / asum[rt][r];
      int l = 32 * wave + 16 * rt + 4 * quad + r;
#pragma unroll
      for (int j = 0; j < 4; ++j)
        Ob[(size_t)l * 1024 + 16 * j + lrow] = f2bf(cacc[rt][j][r] * rinv);
    }
  }
}

// ---------------- O projection: ctx[4096,1024]bf16 @ WtO^T + bias -> fp32 --
// BK=64, swizzled staging + XCD-chunked block swizzle (nwg=512, cpx=64).
__global__ __launch_bounds__(256) void k_gemm_o(
    const u16* __restrict__ ctx, const u16* __restrict__ WtO,
    const u16* __restrict__ bias, float* __restrict__ out) {
  __shared__ u16 As[128 * 64];
  __shared__ u16 Bs[128 * 64];
  int tid = threadIdx.x;
  int wave = tid >> 6, lane = tid & 63;
  int quad = lane >> 4, lrow = lane & 15;
  int wr = wave >> 1, wc = wave & 1;
  // XCD-chunked swizzle: hw id -> work id (grid 8x32x2 = 512, cpx=64)
  int lin = blockIdx.x + 8 * blockIdx.y + 256 * blockIdx.z;
  int s = (lin & 7) * 64 + (lin >> 3);
  int bx = s & 7, by = (s >> 3) & 31, bz = s >> 8;
  int z = bz;
  int m0 = by * 128, n0 = bx * 128;
  const u16* A = ctx + (size_t)z * SIDE;
  const u16* Wt = WtO + (size_t)z * 1048576;
  const u16* bi = bias + (size_t)z * 1024;
  float* C = out + (size_t)z * SIDE;

  f32x4 acc[4][4] = {};
  int srow = 32 * wave + (lane >> 3);
  int ssw = ((lane & 7) ^ (lane >> 3)) * 8;
  const u16* gA = A + (size_t)(m0 + srow) * 1024 + ssw;
  const u16* gB = Wt + (size_t)(n0 + srow) * 1024 + ssw;
  u16* lA = &As[(32 * wave) * 64];
  u16* lB = &Bs[(32 * wave) * 64];

  for (int k0 = 0; k0 < 1024; k0 += 64) {
    __syncthreads();
#pragma unroll
    for (int j = 0; j < 4; ++j) {
      __builtin_amdgcn_global_load_lds((gbl_void*)(gA + (size_t)(8 * j) * 1024 + k0),
                                       (lds_void*)(lA + 8 * j * 64), 16, 0, 0);
      __builtin_amdgcn_global_load_lds((gbl_void*)(gB + (size_t)(8 * j) * 1024 + k0),
                                       (lds_void*)(lB + 8 * j * 64), 16, 0, 0);
    }
    __syncthreads();
#pragma unroll
    for (int kk = 0; kk < 2; ++kk) {
      int gq = ((kk << 2) + quad) ^ (lrow & 7);
      bf16x8 af[4], bfr[4];
#pragma unroll
      for (int i = 0; i < 4; ++i)
        af[i] = *(const bf16x8*)&As[(64 * wr + 16 * i + lrow) * 64 + gq * 8];
#pragma unroll
      for (int j = 0; j < 4; ++j)
        bfr[j] = *(const bf16x8*)&Bs[(64 * wc + 16 * j + lrow) * 64 + gq * 8];
#pragma unroll
      for (int i = 0; i < 4; ++i)
#pragma unroll
        for (int j = 0; j < 4; ++j)
          acc[i][j] = __builtin_amdgcn_mfma_f32_16x16x32_bf16(af[i], bfr[j], acc[i][j], 0, 0, 0);
    }
  }

  float bv[4];
#pragma unroll
  for (int j = 0; j < 4; ++j) bv[j] = bf2f(bi[n0 + 64 * wc + 16 * j + lrow]);
#pragma unroll
  for (int i = 0; i < 4; ++i) {
    int row = m0 + 64 * wr + 16 * i + 4 * quad;
#pragma unroll
    for (int j = 0; j < 4; ++j) {
      int col = n0 + 64 * wc + 16 * j + lrow;
#pragma unroll
      for (int r = 0; r < 4; ++r)
        C[(size_t)(row + r) * 1024 + col] = acc[i][j][r] + bv[j];
    }
  }
}

extern "C" void kernel_launch(void* const* d_in, const int* in_sizes, int n_in,
                              void* d_out, int out_size, void* d_ws, size_t ws_size,
                              hipStream_t stream) {
  (void)in_sizes; (void)n_in; (void)out_size; (void)ws_size;
  const size_t M1 = 1048576u;
  u16* ws = (u16*)d_ws;
  u16* wtA   = ws;             // [2048,1024] concat(Wa_qk^T*0.125*log2e, Wa_v^T)
  u16* wtB   = ws + 2 * M1;    // [2048,1024] concat(Wb_qk^T, Wb_v^T)
  u16* wtO   = ws + 4 * M1;    // [2048,1024] concat(Wa_o^T, Wb_o^T)
  u16* biasQ = ws + 6 * M1;    // [2,2048]
  u16* biasO = ws + 6 * M1 + 4096;  // [2,1024]
  u16* ab    = ws + 7 * M1;    // [2][4096,1024] bf16 inputs (dead after QKV)
  u16* ctx   = ab;             // alias: [2][4096,1024] (attn output)
  u16* qkbuf = ws + 15 * M1;   // [2][bh][2048][64]
  u16* vt    = ws + 23 * M1;   // [2][bh][64][2048] (written by gemm_qkv)

  dim3 blk(256);
  k_cvt_in<<<dim3(2048, 2), blk, 0, stream>>>((const float*)d_in[0],
                                              (const float*)d_in[1], ab);
  k_cvt_bias<<<dim3(4, 6), blk, 0, stream>>>(
      (const float*)d_in[3], (const float*)d_in[5], (const float*)d_in[7],
      (const float*)d_in[9], (const float*)d_in[11], (const float*)d_in[13], biasQ);
  k_transpose_w<<<dim3(16, 16, 6), blk, 0, stream>>>(
      (const float*)d_in[2], (const float*)d_in[4], (const float*)d_in[6],
      (const float*)d_in[8], (const float*)d_in[10], (const float*)d_in[12],
      wtA, wtA + M1, wtB, wtB + M1, wtO, wtO + M1);
  k_gemm_qkv<<<dim3(16, 32, 2), blk, 0, stream>>>(ab, wtA, wtB, biasQ, qkbuf, vt);
  k_attn<<<dim3(32, 16, 2), blk, 0, stream>>>(qkbuf, vt, ctx);
  k_gemm_o<<<dim3(8, 32, 2), blk, 0, stream>>>(ctx, wtO, biasO, (float*)d_out);
}